// Round 1
// baseline (537.782 us; speedup 1.0000x reference)
//
#include <hip/hip_runtime.h>
#include <math.h>

// ---------------------------------------------------------------------------
// K0: coeff[n,j] = b_mat[n,j] * h_vec[n,j],  noise_term[j]
//   h_vec[n,j] = sum_c (sum_k ind[j,k]*h_mat[n,k,c]) * arow[j,c]
//   arow[j,c]  = sum_m a_mat[j,c,m]
//   noise_term[j] = sum_c noise[j,c]*arow[j,c]
// ---------------------------------------------------------------------------
__global__ __launch_bounds__(256) void k_coeff(
    const float* __restrict__ b_mat,     // (10,256)
    const float* __restrict__ h_mat,     // (10,64,5)
    const float* __restrict__ a_mat,     // (256,5,5)
    const float* __restrict__ indicator, // (256,64)
    const float* __restrict__ noise,     // (256,5)
    float* __restrict__ coeff,           // (10,256)
    float* __restrict__ noise_term)      // (256)
{
    int n = blockIdx.x;   // 0..9
    int j = threadIdx.x;  // 0..255
    float arow[5];
#pragma unroll
    for (int c = 0; c < 5; ++c) {
        float s = 0.f;
#pragma unroll
        for (int m = 0; m < 5; ++m) s += a_mat[j * 25 + c * 5 + m];
        arow[c] = s;
    }
    if (n == 0) {
        float nt = 0.f;
#pragma unroll
        for (int c = 0; c < 5; ++c) nt += noise[j * 5 + c] * arow[c];
        noise_term[j] = nt;
    }
    float sc[5] = {0.f, 0.f, 0.f, 0.f, 0.f};
    for (int k = 0; k < 64; ++k) {
        float ind = indicator[j * 64 + k];
#pragma unroll
        for (int c = 0; c < 5; ++c) sc[c] += ind * h_mat[(n * 64 + k) * 5 + c];
    }
    float hv = 0.f;
#pragma unroll
    for (int c = 0; c < 5; ++c) hv += sc[c] * arow[c];
    coeff[n * 256 + j] = b_mat[n * 256 + j] * hv;
}

// ---------------------------------------------------------------------------
// K0b: W_eff[j][k] (256 x 4096, k-contiguous) = cut_w * coeff[n(k), j]
//   k <  2048 : branch n = k/1024 (big),  cut_w_big[n][j][k%1024]
//   k >= 2048 : branch n = 2 + (k-2048)/256, cut_w_small[n-2][j][(k-2048)%256]
// ---------------------------------------------------------------------------
__global__ __launch_bounds__(256) void k_build_w(
    const float* __restrict__ cut_w_big,   // (2,256,1024)
    const float* __restrict__ cut_w_small, // (8,256,256)
    const float* __restrict__ coeff,       // (10,256)
    float* __restrict__ W)                 // (256,4096)
{
    int tid = blockIdx.x * 256 + threadIdx.x; // 0 .. 1048575
    int j = tid >> 12;
    int k = tid & 4095;
    float w;
    int n;
    if (k < 2048) {
        n = k >> 10;
        w = cut_w_big[(n * 256 + j) * 1024 + (k & 1023)];
    } else {
        int kk = k - 2048;
        n = 2 + (kk >> 8);
        w = cut_w_small[((n - 2) * 256 + j) * 256 + (kk & 255)];
    }
    W[tid] = w * coeff[n * 256 + j];
}

// ---------------------------------------------------------------------------
// K1: per-branch conv3x3(pad1) + bias + BN + ReLU + maxpool2x2 -> F (4096x4096)
//   columns: [0,1024) branch0, [1024,2048) branch1, then 8 x 256 small branches
//   big blocks  (bx <  8192): one image each, n = bx>>12, b = bx&4095
//   small blocks (bx >= 8192): 4 images each
// ---------------------------------------------------------------------------
__global__ __launch_bounds__(256) void k_branch(
    const float* __restrict__ x,      // (4096,3,64,64)
    const float* __restrict__ conv_w, // (10,4,3,3,3)
    const float* __restrict__ conv_b, // (10,4)
    const float* __restrict__ bn_g,
    const float* __restrict__ bn_b,
    const float* __restrict__ bn_m,
    const float* __restrict__ bn_v,
    float* __restrict__ F)            // (4096,4096)
{
    __shared__ float in_s[3072];
    __shared__ float bn_a[4], bn_c[4];
    int t = threadIdx.x;
    int bx = blockIdx.x;

    if (bx < 8192) {
        // ---- big branch: 32x32 slice ----
        int n = bx >> 12;      // 0 or 1
        int b = bx & 4095;
        int r0 = 32 * n;
        // stage input slice [ci][y][x] (3x32x32)
        for (int i = t; i < 3072; i += 256) {
            int ci = i >> 10;
            int rem = i & 1023;
            int yy = rem >> 5;
            int xx = rem & 31;
            in_s[i] = x[((size_t)(b * 3 + ci) * 64 + r0 + yy) * 64 + xx];
        }
        if (t < 4) {
            float scale = bn_g[n * 4 + t] * rsqrtf(bn_v[n * 4 + t] + 1e-5f);
            bn_a[t] = scale;
            bn_c[t] = (conv_b[n * 4 + t] - bn_m[n * 4 + t]) * scale + bn_b[n * 4 + t];
        }
        __syncthreads();

        int py = t >> 4, px = t & 15;
        float win[3][4][4];
#pragma unroll
        for (int ci = 0; ci < 3; ++ci)
#pragma unroll
            for (int dy = 0; dy < 4; ++dy) {
                int iy = 2 * py - 1 + dy;
                bool yok = ((unsigned)iy < 32u);
#pragma unroll
                for (int dx = 0; dx < 4; ++dx) {
                    int ix = 2 * px - 1 + dx;
                    win[ci][dy][dx] = (yok && (unsigned)ix < 32u)
                                          ? in_s[ci * 1024 + iy * 32 + ix] : 0.f;
                }
            }
        const float* wp = conv_w + n * 108;
#pragma unroll
        for (int co = 0; co < 4; ++co) {
            float s00 = 0.f, s01 = 0.f, s10 = 0.f, s11 = 0.f;
#pragma unroll
            for (int ci = 0; ci < 3; ++ci)
#pragma unroll
                for (int ky = 0; ky < 3; ++ky)
#pragma unroll
                    for (int kx = 0; kx < 3; ++kx) {
                        float wv = wp[co * 27 + ci * 9 + ky * 3 + kx];
                        s00 += win[ci][ky][kx] * wv;
                        s01 += win[ci][ky][kx + 1] * wv;
                        s10 += win[ci][ky + 1][kx] * wv;
                        s11 += win[ci][ky + 1][kx + 1] * wv;
                    }
            float a = bn_a[co], c2 = bn_c[co];
            float v0 = fmaxf(s00 * a + c2, 0.f);
            float v1 = fmaxf(s01 * a + c2, 0.f);
            float v2 = fmaxf(s10 * a + c2, 0.f);
            float v3 = fmaxf(s11 * a + c2, 0.f);
            float m = fmaxf(fmaxf(v0, v1), fmaxf(v2, v3));
            F[(size_t)b * 4096 + n * 1024 + co * 256 + t] = m;
        }
    } else {
        // ---- small branches: 16x16 slices, 4 images per block ----
        int i2 = bx - 8192;
        int n = 2 + (i2 >> 10);
        int g = i2 & 1023;
        int b0 = g * 4;
        int r0 = 16 * ((n - 2) & 3);
        int c0 = 32 + 16 * ((n - 2) >> 2);
        // stage [ci][img][y][x] (3x4x16x16)
        for (int i = t; i < 3072; i += 256) {
            int ci = i >> 10;
            int rem = i & 1023;
            int img = rem >> 8;
            int yy = (rem >> 4) & 15;
            int xx = rem & 15;
            in_s[i] = x[((size_t)((b0 + img) * 3 + ci) * 64 + r0 + yy) * 64 + c0 + xx];
        }
        if (t < 4) {
            float scale = bn_g[n * 4 + t] * rsqrtf(bn_v[n * 4 + t] + 1e-5f);
            bn_a[t] = scale;
            bn_c[t] = (conv_b[n * 4 + t] - bn_m[n * 4 + t]) * scale + bn_b[n * 4 + t];
        }
        __syncthreads();

        int img = t >> 6;
        int pos = t & 63;
        int py = pos >> 3, px = pos & 7;
        float win[3][4][4];
#pragma unroll
        for (int ci = 0; ci < 3; ++ci)
#pragma unroll
            for (int dy = 0; dy < 4; ++dy) {
                int iy = 2 * py - 1 + dy;
                bool yok = ((unsigned)iy < 16u);
#pragma unroll
                for (int dx = 0; dx < 4; ++dx) {
                    int ix = 2 * px - 1 + dx;
                    win[ci][dy][dx] = (yok && (unsigned)ix < 16u)
                                          ? in_s[ci * 1024 + img * 256 + iy * 16 + ix] : 0.f;
                }
            }
        const float* wp = conv_w + n * 108;
#pragma unroll
        for (int co = 0; co < 4; ++co) {
            float s00 = 0.f, s01 = 0.f, s10 = 0.f, s11 = 0.f;
#pragma unroll
            for (int ci = 0; ci < 3; ++ci)
#pragma unroll
                for (int ky = 0; ky < 3; ++ky)
#pragma unroll
                    for (int kx = 0; kx < 3; ++kx) {
                        float wv = wp[co * 27 + ci * 9 + ky * 3 + kx];
                        s00 += win[ci][ky][kx] * wv;
                        s01 += win[ci][ky][kx + 1] * wv;
                        s10 += win[ci][ky + 1][kx] * wv;
                        s11 += win[ci][ky + 1][kx + 1] * wv;
                    }
            float a = bn_a[co], c2 = bn_c[co];
            float v0 = fmaxf(s00 * a + c2, 0.f);
            float v1 = fmaxf(s01 * a + c2, 0.f);
            float v2 = fmaxf(s10 * a + c2, 0.f);
            float v3 = fmaxf(s11 * a + c2, 0.f);
            float m = fmaxf(fmaxf(v0, v1), fmaxf(v2, v3));
            F[(size_t)(b0 + img) * 4096 + 2048 + (n - 2) * 256 + co * 64 + pos] = m;
        }
    }
}

// ---------------------------------------------------------------------------
// K2: split-K fp32 GEMM.  P[ks][m][j] = sum_{k in slice} F[m][k]*W[j][k]
//   128x128 tile per block, 8x8 per thread, BK=16, KSPLIT=8 -> 512 blocks
// ---------------------------------------------------------------------------
__global__ __launch_bounds__(256) void k_gemm(
    const float* __restrict__ F, // (4096,4096)
    const float* __restrict__ W, // (256,4096)
    float* __restrict__ P)       // (8,4096,256)
{
    __shared__ __align__(16) float As[16][132];
    __shared__ __align__(16) float Bs[16][132];
    int bx = blockIdx.x;
    int tileM = bx & 31;
    int tileJ = (bx >> 5) & 1;
    int ks = bx >> 6;
    int t = threadIdx.x;
    int tx = t & 15, ty = t >> 4;
    int m0 = tileM * 128, j0 = tileJ * 128;
    int k0 = ks * 512;

    float acc[8][8];
#pragma unroll
    for (int i = 0; i < 8; ++i)
#pragma unroll
        for (int j = 0; j < 8; ++j) acc[i][j] = 0.f;

    int lr = t >> 2;
    int lc = (t & 3) << 2;
    const float* Fp = F + (size_t)(m0 + lr) * 4096 + lc;
    const float* Wp = W + (size_t)(j0 + lr) * 4096 + lc;

    for (int kb = k0; kb < k0 + 512; kb += 16) {
        float4 a0 = *(const float4*)(Fp + kb);
        float4 a1 = *(const float4*)(Fp + kb + (size_t)64 * 4096);
        float4 b0 = *(const float4*)(Wp + kb);
        float4 b1 = *(const float4*)(Wp + kb + (size_t)64 * 4096);
        __syncthreads();
        As[lc + 0][lr] = a0.x; As[lc + 1][lr] = a0.y; As[lc + 2][lr] = a0.z; As[lc + 3][lr] = a0.w;
        As[lc + 0][lr + 64] = a1.x; As[lc + 1][lr + 64] = a1.y; As[lc + 2][lr + 64] = a1.z; As[lc + 3][lr + 64] = a1.w;
        Bs[lc + 0][lr] = b0.x; Bs[lc + 1][lr] = b0.y; Bs[lc + 2][lr] = b0.z; Bs[lc + 3][lr] = b0.w;
        Bs[lc + 0][lr + 64] = b1.x; Bs[lc + 1][lr + 64] = b1.y; Bs[lc + 2][lr + 64] = b1.z; Bs[lc + 3][lr + 64] = b1.w;
        __syncthreads();
#pragma unroll
        for (int kk = 0; kk < 16; ++kk) {
            float av[8], bv[8];
            *(float4*)&av[0] = *(const float4*)&As[kk][ty * 8];
            *(float4*)&av[4] = *(const float4*)&As[kk][ty * 8 + 4];
            *(float4*)&bv[0] = *(const float4*)&Bs[kk][tx * 8];
            *(float4*)&bv[4] = *(const float4*)&Bs[kk][tx * 8 + 4];
#pragma unroll
            for (int i = 0; i < 8; ++i)
#pragma unroll
                for (int j = 0; j < 8; ++j) acc[i][j] += av[i] * bv[j];
        }
    }
    float* Pp = P + (size_t)ks * (4096 * 256);
#pragma unroll
    for (int i = 0; i < 8; ++i) {
        int row = m0 + ty * 8 + i;
        float* dst = Pp + (size_t)row * 256 + j0 + tx * 8;
        *(float4*)dst = make_float4(acc[i][0], acc[i][1], acc[i][2], acc[i][3]);
        *(float4*)(dst + 4) = make_float4(acc[i][4], acc[i][5], acc[i][6], acc[i][7]);
    }
}

// ---------------------------------------------------------------------------
// K2b: R = relu(sum_ks P + noise_term)
// ---------------------------------------------------------------------------
__global__ __launch_bounds__(256) void k_reduce(
    const float* __restrict__ P,
    const float* __restrict__ noise_term,
    float* __restrict__ R)
{
    int tid = blockIdx.x * 256 + threadIdx.x; // < 1048576
    float s = noise_term[tid & 255];
#pragma unroll
    for (int ks = 0; ks < 8; ++ks) s += P[(size_t)ks * 1048576 + tid];
    R[tid] = fmaxf(s, 0.f);
}

// ---------------------------------------------------------------------------
// K3: per-row MLP 256->128->64->10 + log_softmax. 16 rows per block.
// ---------------------------------------------------------------------------
__global__ __launch_bounds__(256) void k_mlp(
    const float* __restrict__ R, // (4096,256)
    const float* __restrict__ fc1_w, const float* __restrict__ fc1_b,
    const float* __restrict__ fc2_w, const float* __restrict__ fc2_b,
    const float* __restrict__ out_w, const float* __restrict__ out_b,
    float* __restrict__ out)     // (4096,10)
{
    __shared__ __align__(16) float Rt[16][260];
    __shared__ __align__(16) float H2[16][132];
    __shared__ __align__(16) float H3[16][68];
    __shared__ float LG[16][12];
    __shared__ float mrow[16], srow[16];
    int t = threadIdx.x;
    int b0 = blockIdx.x * 16;

    for (int i = t; i < 1024; i += 256) {
        int r = i >> 6;
        int c4 = i & 63;
        float4 v = *(const float4*)(R + (size_t)(b0 + r) * 256 + c4 * 4);
        *(float4*)&Rt[r][c4 * 4] = v;
    }
    __syncthreads();

    // fc1 + relu
    for (int i = t; i < 2048; i += 256) {
        int r = i & 15, o = i >> 4;
        float s = fc1_b[o];
        const float* wpt = fc1_w + o * 256;
        for (int c = 0; c < 256; c += 4) {
            float4 wv = *(const float4*)(wpt + c);
            float4 rv = *(const float4*)&Rt[r][c];
            s += rv.x * wv.x + rv.y * wv.y + rv.z * wv.z + rv.w * wv.w;
        }
        H2[r][o] = fmaxf(s, 0.f);
    }
    __syncthreads();

    // fc2 + relu
    for (int i = t; i < 1024; i += 256) {
        int r = i & 15, o = i >> 4;
        float s = fc2_b[o];
        const float* wpt = fc2_w + o * 128;
        for (int c = 0; c < 128; c += 4) {
            float4 wv = *(const float4*)(wpt + c);
            float4 rv = *(const float4*)&H2[r][c];
            s += rv.x * wv.x + rv.y * wv.y + rv.z * wv.z + rv.w * wv.w;
        }
        H3[r][o] = fmaxf(s, 0.f);
    }
    __syncthreads();

    // out layer
    if (t < 160) {
        int r = t & 15, o = t >> 4;
        float s = out_b[o];
        const float* wpt = out_w + o * 64;
        for (int c = 0; c < 64; c += 4) {
            float4 wv = *(const float4*)(wpt + c);
            float4 rv = *(const float4*)&H3[r][c];
            s += rv.x * wv.x + rv.y * wv.y + rv.z * wv.z + rv.w * wv.w;
        }
        LG[r][o] = s;
    }
    __syncthreads();

    if (t < 16) {
        float m = -1e30f;
#pragma unroll
        for (int o = 0; o < 10; ++o) m = fmaxf(m, LG[t][o]);
        float s = 0.f;
#pragma unroll
        for (int o = 0; o < 10; ++o) s += expf(LG[t][o] - m);
        mrow[t] = m;
        srow[t] = logf(s);
    }
    __syncthreads();

    if (t < 160) {
        int r = t & 15, o = t >> 4;
        out[(size_t)(b0 + r) * 10 + o] = LG[r][o] - mrow[r] - srow[r];
    }
}

// ---------------------------------------------------------------------------
extern "C" void kernel_launch(void* const* d_in, const int* in_sizes, int n_in,
                              void* d_out, int out_size, void* d_ws, size_t ws_size,
                              hipStream_t stream)
{
    const float* x           = (const float*)d_in[0];
    const float* conv_w      = (const float*)d_in[1];
    const float* conv_b      = (const float*)d_in[2];
    const float* bn_gamma    = (const float*)d_in[3];
    const float* bn_beta     = (const float*)d_in[4];
    const float* bn_mean     = (const float*)d_in[5];
    const float* bn_var      = (const float*)d_in[6];
    const float* cut_w_big   = (const float*)d_in[7];
    const float* cut_w_small = (const float*)d_in[8];
    const float* fc1_w       = (const float*)d_in[9];
    const float* fc1_b       = (const float*)d_in[10];
    const float* fc2_w       = (const float*)d_in[11];
    const float* fc2_b       = (const float*)d_in[12];
    const float* out_w       = (const float*)d_in[13];
    const float* out_b       = (const float*)d_in[14];
    const float* b_mat       = (const float*)d_in[15];
    const float* h_mat       = (const float*)d_in[16];
    const float* a_mat       = (const float*)d_in[17];
    const float* indicator   = (const float*)d_in[18];
    const float* noise       = (const float*)d_in[19];
    float* out = (float*)d_out;

    float* ws = (float*)d_ws;
    float* F     = ws;               // 16777216 floats (64 MB)
    float* W     = F + 16777216;     // 1048576
    float* P     = W + 1048576;      // 8388608 (8 x 1M)
    float* coeff = P + 8388608;      // 2560
    float* nterm = coeff + 2560;     // 256
    float* R     = F;                // reuse F's space (F dead after k_gemm)

    k_coeff<<<10, 256, 0, stream>>>(b_mat, h_mat, a_mat, indicator, noise, coeff, nterm);
    k_build_w<<<4096, 256, 0, stream>>>(cut_w_big, cut_w_small, coeff, W);
    k_branch<<<16384, 256, 0, stream>>>(x, conv_w, conv_b, bn_gamma, bn_beta, bn_mean, bn_var, F);
    k_gemm<<<512, 256, 0, stream>>>(F, W, P);
    k_reduce<<<4096, 256, 0, stream>>>(P, nterm, R);
    k_mlp<<<256, 256, 0, stream>>>(R, fc1_w, fc1_b, fc2_w, fc2_b, out_w, out_b, out);
}

// Round 2
// 455.907 us; speedup vs baseline: 1.1796x; 1.1796x over previous
//
#include <hip/hip_runtime.h>
#include <math.h>

typedef __attribute__((ext_vector_type(8))) short bf16x8;
typedef __attribute__((ext_vector_type(4))) float f32x4;

static __device__ __forceinline__ short f2bf(float f) {
    union { float f; unsigned u; } v; v.f = f;
    unsigned r = v.u + 0x7FFFu + ((v.u >> 16) & 1u);
    return (short)(r >> 16);
}

// ---------------------------------------------------------------------------
// K0: W_eff (bf16, 256 x 4096 k-contiguous) = cut_w * coeff[n(k), j]
// coeff computed in-block: each block covers one (n,j); wave-reduce h_vec.
// ---------------------------------------------------------------------------
__global__ __launch_bounds__(256) void k_build_w(
    const float* __restrict__ cut_w_big,   // (2,256,1024)
    const float* __restrict__ cut_w_small, // (8,256,256)
    const float* __restrict__ b_mat,       // (10,256)
    const float* __restrict__ h_mat,       // (10,64,5)
    const float* __restrict__ a_mat,       // (256,5,5)
    const float* __restrict__ indicator,   // (256,64)
    short* __restrict__ W)                 // (256,4096) bf16
{
    int bx = blockIdx.x;              // 4096 blocks
    int tid0 = bx << 8;
    int j = tid0 >> 12;               // block-uniform
    int kbase = tid0 & 4095;          // block-uniform
    int n = (kbase < 2048) ? (kbase >> 10) : 2 + ((kbase - 2048) >> 8);

    // arow[c] = sum_m a_mat[j,c,m]  (j uniform -> scalarized loads)
    float arow[5];
#pragma unroll
    for (int c = 0; c < 5; ++c) {
        float s = 0.f;
#pragma unroll
        for (int m = 0; m < 5; ++m) s += a_mat[j * 25 + c * 5 + m];
        arow[c] = s;
    }
    // per-lane partial of h_vec: lane = k index (0..63)
    int lane = threadIdx.x & 63;
    float hs = 0.f;
#pragma unroll
    for (int c = 0; c < 5; ++c) hs += h_mat[(n * 64 + lane) * 5 + c] * arow[c];
    float v = indicator[j * 64 + lane] * hs;
#pragma unroll
    for (int off = 32; off >= 1; off >>= 1) v += __shfl_xor(v, off);
    float coeff = b_mat[n * 256 + j] * v;

    int tid = tid0 + threadIdx.x;
    int k = tid & 4095;
    float w;
    if (k < 2048) {
        w = cut_w_big[(((k >> 10) * 256 + j) << 10) + (k & 1023)];
    } else {
        int kk = k - 2048;
        w = cut_w_small[(((kk >> 8) * 256 + j) << 8) + (kk & 255)];
    }
    W[tid] = f2bf(w * coeff);
}

// ---------------------------------------------------------------------------
// K1: conv3x3(pad1)+bias+BN+ReLU+pool2x2 -> F (4096x4096 bf16)
// Zero-padded LDS tile: no bounds predication in the hot loop.
// ---------------------------------------------------------------------------
__global__ __launch_bounds__(256) void k_branch(
    const float* __restrict__ x,      // (4096,3,64,64)
    const float* __restrict__ conv_w, // (10,4,3,3,3)
    const float* __restrict__ conv_b,
    const float* __restrict__ bn_g,
    const float* __restrict__ bn_b,
    const float* __restrict__ bn_m,
    const float* __restrict__ bn_v,
    short* __restrict__ F)            // (4096,4096) bf16
{
    __shared__ float in_s[4320];      // max(3*34*36=3672, 3*4*18*20=4320)
    __shared__ float bn_a[4], bn_c[4];
    int t = threadIdx.x;
    int bx = blockIdx.x;

    // zero the whole tile (cheap; removes all bounds checks later)
    for (int i = t; i < 4320; i += 256) in_s[i] = 0.f;
    __syncthreads();

    if (bx < 8192) {
        // ---- big branch: 32x32 slice, 1 image/block ----
        int n = bx >> 12;
        int b = bx & 4095;
        int r0 = 32 * n;
        // tile [3][34][36], interior at (ry=yy+1, cx=xx+1)
        for (int i = t; i < 3072; i += 256) {
            int ci = i >> 10;
            int rem = i & 1023;
            int yy = rem >> 5;
            int xx = rem & 31;
            in_s[ci * 1224 + (yy + 1) * 36 + (xx + 1)] =
                x[((size_t)(b * 3 + ci) * 64 + r0 + yy) * 64 + xx];
        }
        if (t < 4) {
            float scale = bn_g[n * 4 + t] * rsqrtf(bn_v[n * 4 + t] + 1e-5f);
            bn_a[t] = scale;
            bn_c[t] = (conv_b[n * 4 + t] - bn_m[n * 4 + t]) * scale + bn_b[n * 4 + t];
        }
        __syncthreads();

        int py = t >> 4, px = t & 15;
        float win[3][4][4];
#pragma unroll
        for (int ci = 0; ci < 3; ++ci)
#pragma unroll
            for (int dy = 0; dy < 4; ++dy)
#pragma unroll
                for (int dx = 0; dx < 4; ++dx)
                    win[ci][dy][dx] = in_s[ci * 1224 + (2 * py + dy) * 36 + (2 * px + dx)];
        const float* wp = conv_w + n * 108;
#pragma unroll
        for (int co = 0; co < 4; ++co) {
            float s00 = 0.f, s01 = 0.f, s10 = 0.f, s11 = 0.f;
#pragma unroll
            for (int ci = 0; ci < 3; ++ci)
#pragma unroll
                for (int ky = 0; ky < 3; ++ky)
#pragma unroll
                    for (int kx = 0; kx < 3; ++kx) {
                        float wv = wp[co * 27 + ci * 9 + ky * 3 + kx];
                        s00 += win[ci][ky][kx] * wv;
                        s01 += win[ci][ky][kx + 1] * wv;
                        s10 += win[ci][ky + 1][kx] * wv;
                        s11 += win[ci][ky + 1][kx + 1] * wv;
                    }
            float a = bn_a[co], c2 = bn_c[co];
            float v0 = fmaxf(s00 * a + c2, 0.f);
            float v1 = fmaxf(s01 * a + c2, 0.f);
            float v2 = fmaxf(s10 * a + c2, 0.f);
            float v3 = fmaxf(s11 * a + c2, 0.f);
            F[(size_t)b * 4096 + n * 1024 + co * 256 + t] =
                f2bf(fmaxf(fmaxf(v0, v1), fmaxf(v2, v3)));
        }
    } else {
        // ---- small branches: 16x16 slices, 4 images/block ----
        int i2 = bx - 8192;
        int n = 2 + (i2 >> 10);
        int g = i2 & 1023;
        int b0 = g * 4;
        int r0 = 16 * ((n - 2) & 3);
        int c0 = 32 + 16 * ((n - 2) >> 2);
        // tile [3][4][18][20]
        for (int i = t; i < 3072; i += 256) {
            int ci = i >> 10;
            int rem = i & 1023;
            int img = rem >> 8;
            int yy = (rem >> 4) & 15;
            int xx = rem & 15;
            in_s[((ci * 4 + img) * 18 + yy + 1) * 20 + xx + 1] =
                x[((size_t)((b0 + img) * 3 + ci) * 64 + r0 + yy) * 64 + c0 + xx];
        }
        if (t < 4) {
            float scale = bn_g[n * 4 + t] * rsqrtf(bn_v[n * 4 + t] + 1e-5f);
            bn_a[t] = scale;
            bn_c[t] = (conv_b[n * 4 + t] - bn_m[n * 4 + t]) * scale + bn_b[n * 4 + t];
        }
        __syncthreads();

        int img = t >> 6;
        int pos = t & 63;
        int py = pos >> 3, px = pos & 7;
        float win[3][4][4];
#pragma unroll
        for (int ci = 0; ci < 3; ++ci)
#pragma unroll
            for (int dy = 0; dy < 4; ++dy)
#pragma unroll
                for (int dx = 0; dx < 4; ++dx)
                    win[ci][dy][dx] =
                        in_s[((ci * 4 + img) * 18 + 2 * py + dy) * 20 + (2 * px + dx)];
        const float* wp = conv_w + n * 108;
#pragma unroll
        for (int co = 0; co < 4; ++co) {
            float s00 = 0.f, s01 = 0.f, s10 = 0.f, s11 = 0.f;
#pragma unroll
            for (int ci = 0; ci < 3; ++ci)
#pragma unroll
                for (int ky = 0; ky < 3; ++ky)
#pragma unroll
                    for (int kx = 0; kx < 3; ++kx) {
                        float wv = wp[co * 27 + ci * 9 + ky * 3 + kx];
                        s00 += win[ci][ky][kx] * wv;
                        s01 += win[ci][ky][kx + 1] * wv;
                        s10 += win[ci][ky + 1][kx] * wv;
                        s11 += win[ci][ky + 1][kx + 1] * wv;
                    }
            float a = bn_a[co], c2 = bn_c[co];
            float v0 = fmaxf(s00 * a + c2, 0.f);
            float v1 = fmaxf(s01 * a + c2, 0.f);
            float v2 = fmaxf(s10 * a + c2, 0.f);
            float v3 = fmaxf(s11 * a + c2, 0.f);
            F[(size_t)(b0 + img) * 4096 + 2048 + (n - 2) * 256 + co * 64 + pos] =
                f2bf(fmaxf(fmaxf(v0, v1), fmaxf(v2, v3)));
        }
    }
}

// ---------------------------------------------------------------------------
// K2: bf16 MFMA GEMM (both operands k-contiguous), split-K=8.
// P[ks][m][j] = sum_{k in slice} F[m][k]*W[j][k]
// 128x128 tile, BK=64, global_load_lds(16B), XOR-swizzled k-segments.
// ---------------------------------------------------------------------------
__global__ __launch_bounds__(256) void k_gemm(
    const short* __restrict__ F, // (4096,4096) bf16
    const short* __restrict__ W, // (256,4096) bf16
    float* __restrict__ P)       // (8,4096,256)
{
    __shared__ short As[128 * 64];
    __shared__ short Bs[128 * 64];
    int bx = blockIdx.x;          // 512 = 32 mtiles x 2 jtiles x 8 ksplit
    int mt = bx & 31;
    int jt = (bx >> 5) & 1;
    int ks = bx >> 6;
    int t = threadIdx.x;
    int m0 = mt << 7, j0 = jt << 7;

    int lane = t & 63;
    int wave = t >> 6;
    int wm = wave & 1, wn = wave >> 1;
    int l16 = lane & 15, quad = lane >> 4;

    f32x4 acc[4][4];
#pragma unroll
    for (int i = 0; i < 4; ++i)
#pragma unroll
        for (int j = 0; j < 4; ++j) acc[i][j] = (f32x4){0.f, 0.f, 0.f, 0.f};

    for (int it = 0; it < 8; ++it) {
        int k0 = (ks << 9) + (it << 6);
        // stage A and B tiles: 1024 chunks of 16B each
#pragma unroll
        for (int r = 0; r < 4; ++r) {
            int c = (r << 8) + t;      // chunk 0..1023
            int row = c >> 3, s = c & 7;
            int g = s ^ (row & 7);     // XOR swizzle of k-segment
            const short* gpA = F + ((size_t)(m0 + row) << 12) + k0 + (g << 3);
            const short* gpB = W + ((size_t)(j0 + row) << 12) + k0 + (g << 3);
            __builtin_amdgcn_global_load_lds(
                (const __attribute__((address_space(1))) void*)gpA,
                (__attribute__((address_space(3))) void*)(As + (c << 3)), 16, 0, 0);
            __builtin_amdgcn_global_load_lds(
                (const __attribute__((address_space(1))) void*)gpB,
                (__attribute__((address_space(3))) void*)(Bs + (c << 3)), 16, 0, 0);
        }
        __syncthreads();
#pragma unroll
        for (int ks2 = 0; ks2 < 2; ++ks2) {
            bf16x8 af[4], bfr[4];
#pragma unroll
            for (int mi = 0; mi < 4; ++mi) {
                int row = (wm << 6) + (mi << 4) + l16;
                int q = (ks2 << 2) + quad;
                int sl = q ^ (row & 7);
                af[mi] = *(const bf16x8*)&As[(row << 6) + (sl << 3)];
            }
#pragma unroll
            for (int ni = 0; ni < 4; ++ni) {
                int row = (wn << 6) + (ni << 4) + l16;
                int q = (ks2 << 2) + quad;
                int sl = q ^ (row & 7);
                bfr[ni] = *(const bf16x8*)&Bs[(row << 6) + (sl << 3)];
            }
#pragma unroll
            for (int mi = 0; mi < 4; ++mi)
#pragma unroll
                for (int ni = 0; ni < 4; ++ni)
                    acc[mi][ni] = __builtin_amdgcn_mfma_f32_16x16x32_bf16(
                        af[mi], bfr[ni], acc[mi][ni], 0, 0, 0);
        }
        __syncthreads();
    }

    float* Pp = P + ((size_t)ks << 20);
#pragma unroll
    for (int mi = 0; mi < 4; ++mi)
#pragma unroll
        for (int ni = 0; ni < 4; ++ni) {
            int col = j0 + (wn << 6) + (ni << 4) + l16;
#pragma unroll
            for (int r = 0; r < 4; ++r) {
                int row = m0 + (wm << 6) + (mi << 4) + (quad << 2) + r;
                Pp[(size_t)row * 256 + col] = acc[mi][ni][r];
            }
        }
}

// ---------------------------------------------------------------------------
// K2b: R = relu(sum_ks P + noise_term); noise_term computed in-place.
// One block per image, thread j = 0..255.
// ---------------------------------------------------------------------------
__global__ __launch_bounds__(256) void k_reduce(
    const float* __restrict__ P,
    const float* __restrict__ a_mat,  // (256,5,5)
    const float* __restrict__ noise,  // (256,5)
    float* __restrict__ R)
{
    int b = blockIdx.x;
    int j = threadIdx.x;
    float nt = 0.f;
#pragma unroll
    for (int c = 0; c < 5; ++c) {
        float ar = 0.f;
#pragma unroll
        for (int m = 0; m < 5; ++m) ar += a_mat[j * 25 + c * 5 + m];
        nt += noise[j * 5 + c] * ar;
    }
    float s = nt;
    size_t base = (size_t)b * 256 + j;
#pragma unroll
    for (int ks = 0; ks < 8; ++ks) s += P[((size_t)ks << 20) + base];
    R[base] = fmaxf(s, 0.f);
}

// ---------------------------------------------------------------------------
// K3: per-row MLP 256->128->64->10 + log_softmax. 8 rows/block, 512 blocks.
// ---------------------------------------------------------------------------
__global__ __launch_bounds__(256) void k_mlp(
    const float* __restrict__ R, // (4096,256)
    const float* __restrict__ fc1_w, const float* __restrict__ fc1_b,
    const float* __restrict__ fc2_w, const float* __restrict__ fc2_b,
    const float* __restrict__ out_w, const float* __restrict__ out_b,
    float* __restrict__ out)     // (4096,10)
{
    __shared__ __align__(16) float Rt[8][260];
    __shared__ __align__(16) float H2[8][132];
    __shared__ __align__(16) float H3[8][68];
    __shared__ float LG[8][12];
    __shared__ float mrow[8], srow[8];
    int t = threadIdx.x;
    int b0 = blockIdx.x * 8;

    for (int i = t; i < 512; i += 256) {
        int r = i >> 6;
        int c4 = i & 63;
        *(float4*)&Rt[r][c4 * 4] = *(const float4*)(R + (size_t)(b0 + r) * 256 + c4 * 4);
    }
    __syncthreads();

    // fc1 + relu: 1024 outputs, 4/thread
    for (int i = t; i < 1024; i += 256) {
        int r = i & 7, o = i >> 3;
        float s = fc1_b[o];
        const float* wpt = fc1_w + o * 256;
        for (int c = 0; c < 256; c += 4) {
            float4 wv = *(const float4*)(wpt + c);
            float4 rv = *(const float4*)&Rt[r][c];
            s += rv.x * wv.x + rv.y * wv.y + rv.z * wv.z + rv.w * wv.w;
        }
        H2[r][o] = fmaxf(s, 0.f);
    }
    __syncthreads();

    // fc2 + relu: 512 outputs, 2/thread
    for (int i = t; i < 512; i += 256) {
        int r = i & 7, o = i >> 3;
        float s = fc2_b[o];
        const float* wpt = fc2_w + o * 128;
        for (int c = 0; c < 128; c += 4) {
            float4 wv = *(const float4*)(wpt + c);
            float4 rv = *(const float4*)&H2[r][c];
            s += rv.x * wv.x + rv.y * wv.y + rv.z * wv.z + rv.w * wv.w;
        }
        H3[r][o] = fmaxf(s, 0.f);
    }
    __syncthreads();

    if (t < 80) {
        int r = t & 7, o = t >> 3;
        float s = out_b[o];
        const float* wpt = out_w + o * 64;
        for (int c = 0; c < 64; c += 4) {
            float4 wv = *(const float4*)(wpt + c);
            float4 rv = *(const float4*)&H3[r][c];
            s += rv.x * wv.x + rv.y * wv.y + rv.z * wv.z + rv.w * wv.w;
        }
        LG[r][o] = s;
    }
    __syncthreads();

    if (t < 8) {
        float m = -1e30f;
#pragma unroll
        for (int o = 0; o < 10; ++o) m = fmaxf(m, LG[t][o]);
        float s = 0.f;
#pragma unroll
        for (int o = 0; o < 10; ++o) s += expf(LG[t][o] - m);
        mrow[t] = m;
        srow[t] = logf(s);
    }
    __syncthreads();

    if (t < 80) {
        int r = t & 7, o = t >> 3;
        out[(size_t)(b0 + r) * 10 + o] = LG[r][o] - mrow[r] - srow[r];
    }
}

// ---------------------------------------------------------------------------
extern "C" void kernel_launch(void* const* d_in, const int* in_sizes, int n_in,
                              void* d_out, int out_size, void* d_ws, size_t ws_size,
                              hipStream_t stream)
{
    const float* x           = (const float*)d_in[0];
    const float* conv_w      = (const float*)d_in[1];
    const float* conv_b      = (const float*)d_in[2];
    const float* bn_gamma    = (const float*)d_in[3];
    const float* bn_beta     = (const float*)d_in[4];
    const float* bn_mean     = (const float*)d_in[5];
    const float* bn_var      = (const float*)d_in[6];
    const float* cut_w_big   = (const float*)d_in[7];
    const float* cut_w_small = (const float*)d_in[8];
    const float* fc1_w       = (const float*)d_in[9];
    const float* fc1_b       = (const float*)d_in[10];
    const float* fc2_w       = (const float*)d_in[11];
    const float* fc2_b       = (const float*)d_in[12];
    const float* out_w       = (const float*)d_in[13];
    const float* out_b       = (const float*)d_in[14];
    const float* b_mat       = (const float*)d_in[15];
    const float* h_mat       = (const float*)d_in[16];
    const float* a_mat       = (const float*)d_in[17];
    const float* indicator   = (const float*)d_in[18];
    const float* noise       = (const float*)d_in[19];
    float* out = (float*)d_out;

    char* ws = (char*)d_ws;
    short* Fbf = (short*)ws;                     // 32 MB (16.7M bf16)
    short* Wbf = (short*)(ws + 33554432);        // 2 MB
    float* P   = (float*)(ws + 35651584);        // 32 MB (8 x 1M fp32)
    float* R   = (float*)(ws + 69206016);        // 4 MB

    k_build_w<<<4096, 256, 0, stream>>>(cut_w_big, cut_w_small, b_mat, h_mat,
                                        a_mat, indicator, Wbf);
    k_branch<<<16384, 256, 0, stream>>>(x, conv_w, conv_b, bn_gamma, bn_beta,
                                        bn_mean, bn_var, Fbf);
    k_gemm<<<512, 256, 0, stream>>>(Fbf, Wbf, P);
    k_reduce<<<4096, 256, 0, stream>>>(P, a_mat, noise, R);
    k_mlp<<<512, 256, 0, stream>>>(R, fc1_w, fc1_b, fc2_w, fc2_b, out_w, out_b, out);
}

// Round 3
// 423.185 us; speedup vs baseline: 1.2708x; 1.0773x over previous
//
#include <hip/hip_runtime.h>
#include <math.h>

typedef __attribute__((ext_vector_type(8))) short bf16x8;
typedef __attribute__((ext_vector_type(4))) float f32x4;

static __device__ __forceinline__ short f2bf(float f) {
    union { float f; unsigned u; } v; v.f = f;
    unsigned r = v.u + 0x7FFFu + ((v.u >> 16) & 1u);
    return (short)(r >> 16);
}

// ---------------------------------------------------------------------------
// Physical k-layout of F / W columns (4096), co packed innermost:
//   big n in {0,1}:   phys = n*1024 + pos*4 + co    (pos 0..255, logical kk = co*256+pos)
//   small n in {2..9}: phys = 2048 + (n-2)*256 + pos*4 + co (pos 0..63, kk = co*64+pos)
// ---------------------------------------------------------------------------

// K0: W_eff (bf16, 256 x 4096 phys-k) = cut_w * coeff[n(k), j]
__global__ __launch_bounds__(256) void k_build_w(
    const float* __restrict__ cut_w_big,   // (2,256,1024)
    const float* __restrict__ cut_w_small, // (8,256,256)
    const float* __restrict__ b_mat,       // (10,256)
    const float* __restrict__ h_mat,       // (10,64,5)
    const float* __restrict__ a_mat,       // (256,5,5)
    const float* __restrict__ indicator,   // (256,64)
    short* __restrict__ W)                 // (256,4096) bf16
{
    int bx = blockIdx.x;              // 4096 blocks
    int tid0 = bx << 8;
    int j = tid0 >> 12;               // block-uniform
    int kbase = tid0 & 4095;          // block-uniform
    int n = (kbase < 2048) ? (kbase >> 10) : 2 + ((kbase - 2048) >> 8);

    float arow[5];
#pragma unroll
    for (int c = 0; c < 5; ++c) {
        float s = 0.f;
#pragma unroll
        for (int m = 0; m < 5; ++m) s += a_mat[j * 25 + c * 5 + m];
        arow[c] = s;
    }
    int lane = threadIdx.x & 63;
    float hs = 0.f;
#pragma unroll
    for (int c = 0; c < 5; ++c) hs += h_mat[(n * 64 + lane) * 5 + c] * arow[c];
    float v = indicator[j * 64 + lane] * hs;
#pragma unroll
    for (int off = 32; off >= 1; off >>= 1) v += __shfl_xor(v, off);
    float coeff = b_mat[n * 256 + j] * v;

    int tid = tid0 + threadIdx.x;
    int k = tid & 4095;
    float w;
    if (k < 2048) {
        int nn = k >> 10;
        int r = k & 1023;
        int pos = r >> 2, co = r & 3;
        w = cut_w_big[((nn * 256 + j) << 10) + co * 256 + pos];
    } else {
        int kk2 = k - 2048;
        int nn = kk2 >> 8;
        int r = kk2 & 255;
        int pos = r >> 2, co = r & 3;
        w = cut_w_small[((nn * 256 + j) << 8) + co * 64 + pos];
    }
    W[tid] = f2bf(w * coeff);
}

// ---------------------------------------------------------------------------
// K1: conv3x3(pad1)+bias+BN+ReLU+pool2x2 -> F (4096x4096 bf16, phys-k layout)
// Register-resident per-ci window (16 floats), halo-only zeroing, float4
// staging, packed short4 stores.
// ---------------------------------------------------------------------------
__global__ __launch_bounds__(256) void k_branch(
    const float* __restrict__ x,      // (4096,3,64,64)
    const float* __restrict__ conv_w, // (10,4,3,3,3)
    const float* __restrict__ conv_b,
    const float* __restrict__ bn_g,
    const float* __restrict__ bn_b,
    const float* __restrict__ bn_m,
    const float* __restrict__ bn_v,
    short* __restrict__ F)            // (4096,4096) bf16
{
    // big:   3 pages of 34x40 (interior rows 1..32, cols 4..35) = 4080 floats
    // small: 12 pages of 18x24 (interior rows 1..16, cols 4..19) = 5184 floats
    __shared__ float in_s[5184];
    __shared__ float bn_a[4], bn_c[4];
    int t = threadIdx.x;
    int bx = blockIdx.x;

    if (bx < 8192) {
        // ---- big branch: 32x32 slice, 1 image/block ----
        int n = bx >> 12;
        int b = bx & 4095;
        int r0 = 32 * n;
        // halo zero: per ci: row0[3..36], row33[3..36], col3[0..33], col36[0..33]
        for (int i = t; i < 408; i += 256) {
            int ci = i / 136, rem = i % 136;
            int seg = rem / 34, off = rem % 34;
            int addr;
            if (seg == 0)      addr = ci * 1360 + 3 + off;
            else if (seg == 1) addr = ci * 1360 + 33 * 40 + 3 + off;
            else if (seg == 2) addr = ci * 1360 + off * 40 + 3;
            else               addr = ci * 1360 + off * 40 + 36;
            in_s[addr] = 0.f;
        }
        // stage interior: 768 float4 (3/thread)
        for (int i = t; i < 768; i += 256) {
            int ci = i >> 8, rem = i & 255, yy = rem >> 3, xq = rem & 7;
            float4 v = *(const float4*)(x + ((size_t)(b * 3 + ci) * 64 + r0 + yy) * 64 + xq * 4);
            *(float4*)&in_s[ci * 1360 + (yy + 1) * 40 + 4 + xq * 4] = v;
        }
        if (t < 4) {
            float scale = bn_g[n * 4 + t] * rsqrtf(bn_v[n * 4 + t] + 1e-5f);
            bn_a[t] = scale;
            bn_c[t] = (conv_b[n * 4 + t] - bn_m[n * 4 + t]) * scale + bn_b[n * 4 + t];
        }
        __syncthreads();

        int py = t >> 4, px = t & 15;
        float s[4][4];
#pragma unroll
        for (int a = 0; a < 4; ++a)
#pragma unroll
            for (int p = 0; p < 4; ++p) s[a][p] = 0.f;
        const float* wp = conv_w + n * 108;
#pragma unroll
        for (int ci = 0; ci < 3; ++ci) {
            float wv[16];
            int base = ci * 1360 + (2 * py) * 40 + 3 + 2 * px;
#pragma unroll
            for (int dy = 0; dy < 4; ++dy)
#pragma unroll
                for (int dx = 0; dx < 4; ++dx)
                    wv[dy * 4 + dx] = in_s[base + dy * 40 + dx];
#pragma unroll
            for (int co = 0; co < 4; ++co) {
                const float* kk = wp + co * 27 + ci * 9;
                float k0 = kk[0], k1 = kk[1], k2 = kk[2], k3 = kk[3], k4 = kk[4],
                      k5 = kk[5], k6 = kk[6], k7 = kk[7], k8 = kk[8];
                s[co][0] += wv[0] * k0 + wv[1] * k1 + wv[2] * k2 + wv[4] * k3 + wv[5] * k4 + wv[6] * k5 + wv[8] * k6 + wv[9] * k7 + wv[10] * k8;
                s[co][1] += wv[1] * k0 + wv[2] * k1 + wv[3] * k2 + wv[5] * k3 + wv[6] * k4 + wv[7] * k5 + wv[9] * k6 + wv[10] * k7 + wv[11] * k8;
                s[co][2] += wv[4] * k0 + wv[5] * k1 + wv[6] * k2 + wv[8] * k3 + wv[9] * k4 + wv[10] * k5 + wv[12] * k6 + wv[13] * k7 + wv[14] * k8;
                s[co][3] += wv[5] * k0 + wv[6] * k1 + wv[7] * k2 + wv[9] * k3 + wv[10] * k4 + wv[11] * k5 + wv[13] * k6 + wv[14] * k7 + wv[15] * k8;
            }
        }
        short4 pk;
        {
            float m[4];
#pragma unroll
            for (int co = 0; co < 4; ++co) {
                float a = bn_a[co], c2 = bn_c[co];
                float v0 = fmaxf(s[co][0] * a + c2, 0.f);
                float v1 = fmaxf(s[co][1] * a + c2, 0.f);
                float v2 = fmaxf(s[co][2] * a + c2, 0.f);
                float v3 = fmaxf(s[co][3] * a + c2, 0.f);
                m[co] = fmaxf(fmaxf(v0, v1), fmaxf(v2, v3));
            }
            pk.x = f2bf(m[0]); pk.y = f2bf(m[1]); pk.z = f2bf(m[2]); pk.w = f2bf(m[3]);
        }
        *(short4*)&F[(size_t)b * 4096 + n * 1024 + t * 4] = pk;
    } else {
        // ---- small branches: 16x16 slices, 4 images/block ----
        int i2 = bx - 8192;
        int n = 2 + (i2 >> 10);
        int g = i2 & 1023;
        int b0 = g * 4;
        int r0 = 16 * ((n - 2) & 3);
        int c0 = 32 + 16 * ((n - 2) >> 2);
        // halo zero: per page (12): row0[3..20], row17[3..20], col3[0..17], col20[0..17]
        for (int i = t; i < 864; i += 256) {
            int page = i / 72, rem = i % 72;
            int seg = rem / 18, off = rem % 18;
            int addr;
            if (seg == 0)      addr = page * 432 + 3 + off;
            else if (seg == 1) addr = page * 432 + 17 * 24 + 3 + off;
            else if (seg == 2) addr = page * 432 + off * 24 + 3;
            else               addr = page * 432 + off * 24 + 20;
            in_s[addr] = 0.f;
        }
        // stage interior: 768 float4 (3/thread), page = ci*4+img
        for (int i = t; i < 768; i += 256) {
            int page = i >> 6, rem = i & 63, yy = rem >> 2, xq = rem & 3;
            int ci = page >> 2, img = page & 3;
            float4 v = *(const float4*)(x + ((size_t)((b0 + img) * 3 + ci) * 64 + r0 + yy) * 64 + c0 + xq * 4);
            *(float4*)&in_s[page * 432 + (yy + 1) * 24 + 4 + xq * 4] = v;
        }
        if (t < 4) {
            float scale = bn_g[n * 4 + t] * rsqrtf(bn_v[n * 4 + t] + 1e-5f);
            bn_a[t] = scale;
            bn_c[t] = (conv_b[n * 4 + t] - bn_m[n * 4 + t]) * scale + bn_b[n * 4 + t];
        }
        __syncthreads();

        int img = t >> 6;
        int pos = t & 63;
        int py = pos >> 3, px = pos & 7;
        float s[4][4];
#pragma unroll
        for (int a = 0; a < 4; ++a)
#pragma unroll
            for (int p = 0; p < 4; ++p) s[a][p] = 0.f;
        const float* wp = conv_w + n * 108;
#pragma unroll
        for (int ci = 0; ci < 3; ++ci) {
            float wv[16];
            int base = (ci * 4 + img) * 432 + (2 * py) * 24 + 3 + 2 * px;
#pragma unroll
            for (int dy = 0; dy < 4; ++dy)
#pragma unroll
                for (int dx = 0; dx < 4; ++dx)
                    wv[dy * 4 + dx] = in_s[base + dy * 24 + dx];
#pragma unroll
            for (int co = 0; co < 4; ++co) {
                const float* kk = wp + co * 27 + ci * 9;
                float k0 = kk[0], k1 = kk[1], k2 = kk[2], k3 = kk[3], k4 = kk[4],
                      k5 = kk[5], k6 = kk[6], k7 = kk[7], k8 = kk[8];
                s[co][0] += wv[0] * k0 + wv[1] * k1 + wv[2] * k2 + wv[4] * k3 + wv[5] * k4 + wv[6] * k5 + wv[8] * k6 + wv[9] * k7 + wv[10] * k8;
                s[co][1] += wv[1] * k0 + wv[2] * k1 + wv[3] * k2 + wv[5] * k3 + wv[6] * k4 + wv[7] * k5 + wv[9] * k6 + wv[10] * k7 + wv[11] * k8;
                s[co][2] += wv[4] * k0 + wv[5] * k1 + wv[6] * k2 + wv[8] * k3 + wv[9] * k4 + wv[10] * k5 + wv[12] * k6 + wv[13] * k7 + wv[14] * k8;
                s[co][3] += wv[5] * k0 + wv[6] * k1 + wv[7] * k2 + wv[9] * k3 + wv[10] * k4 + wv[11] * k5 + wv[13] * k6 + wv[14] * k7 + wv[15] * k8;
            }
        }
        short4 pk;
        {
            float m[4];
#pragma unroll
            for (int co = 0; co < 4; ++co) {
                float a = bn_a[co], c2 = bn_c[co];
                float v0 = fmaxf(s[co][0] * a + c2, 0.f);
                float v1 = fmaxf(s[co][1] * a + c2, 0.f);
                float v2 = fmaxf(s[co][2] * a + c2, 0.f);
                float v3 = fmaxf(s[co][3] * a + c2, 0.f);
                m[co] = fmaxf(fmaxf(v0, v1), fmaxf(v2, v3));
            }
            pk.x = f2bf(m[0]); pk.y = f2bf(m[1]); pk.z = f2bf(m[2]); pk.w = f2bf(m[3]);
        }
        *(short4*)&F[(size_t)(b0 + img) * 4096 + 2048 + (n - 2) * 256 + pos * 4] = pk;
    }
}

// ---------------------------------------------------------------------------
// K2: bf16 MFMA GEMM, split-K=8 (unchanged from R2 — ~matches its prediction)
// ---------------------------------------------------------------------------
__global__ __launch_bounds__(256) void k_gemm(
    const short* __restrict__ F, // (4096,4096) bf16
    const short* __restrict__ W, // (256,4096) bf16
    float* __restrict__ P)       // (8,4096,256)
{
    __shared__ short As[128 * 64];
    __shared__ short Bs[128 * 64];
    int bx = blockIdx.x;          // 512 = 32 mtiles x 2 jtiles x 8 ksplit
    int mt = bx & 31;
    int jt = (bx >> 5) & 1;
    int ks = bx >> 6;
    int t = threadIdx.x;
    int m0 = mt << 7, j0 = jt << 7;

    int lane = t & 63;
    int wave = t >> 6;
    int wm = wave & 1, wn = wave >> 1;
    int l16 = lane & 15, quad = lane >> 4;

    f32x4 acc[4][4];
#pragma unroll
    for (int i = 0; i < 4; ++i)
#pragma unroll
        for (int j = 0; j < 4; ++j) acc[i][j] = (f32x4){0.f, 0.f, 0.f, 0.f};

    for (int it = 0; it < 8; ++it) {
        int k0 = (ks << 9) + (it << 6);
#pragma unroll
        for (int r = 0; r < 4; ++r) {
            int c = (r << 8) + t;
            int row = c >> 3, sgl = c & 7;
            int gsw = sgl ^ (row & 7);
            const short* gpA = F + ((size_t)(m0 + row) << 12) + k0 + (gsw << 3);
            const short* gpB = W + ((size_t)(j0 + row) << 12) + k0 + (gsw << 3);
            __builtin_amdgcn_global_load_lds(
                (const __attribute__((address_space(1))) void*)gpA,
                (__attribute__((address_space(3))) void*)(As + (c << 3)), 16, 0, 0);
            __builtin_amdgcn_global_load_lds(
                (const __attribute__((address_space(1))) void*)gpB,
                (__attribute__((address_space(3))) void*)(Bs + (c << 3)), 16, 0, 0);
        }
        __syncthreads();
#pragma unroll
        for (int ks2 = 0; ks2 < 2; ++ks2) {
            bf16x8 af[4], bfr[4];
#pragma unroll
            for (int mi = 0; mi < 4; ++mi) {
                int row = (wm << 6) + (mi << 4) + l16;
                int q = (ks2 << 2) + quad;
                int sl = q ^ (row & 7);
                af[mi] = *(const bf16x8*)&As[(row << 6) + (sl << 3)];
            }
#pragma unroll
            for (int ni = 0; ni < 4; ++ni) {
                int row = (wn << 6) + (ni << 4) + l16;
                int q = (ks2 << 2) + quad;
                int sl = q ^ (row & 7);
                bfr[ni] = *(const bf16x8*)&Bs[(row << 6) + (sl << 3)];
            }
#pragma unroll
            for (int mi = 0; mi < 4; ++mi)
#pragma unroll
                for (int ni = 0; ni < 4; ++ni)
                    acc[mi][ni] = __builtin_amdgcn_mfma_f32_16x16x32_bf16(
                        af[mi], bfr[ni], acc[mi][ni], 0, 0, 0);
        }
        __syncthreads();
    }

    float* Pp = P + ((size_t)ks << 20);
#pragma unroll
    for (int mi = 0; mi < 4; ++mi)
#pragma unroll
        for (int ni = 0; ni < 4; ++ni) {
            int col = j0 + (wn << 6) + (ni << 4) + l16;
#pragma unroll
            for (int r = 0; r < 4; ++r) {
                int row = m0 + (wm << 6) + (mi << 4) + (quad << 2) + r;
                Pp[(size_t)row * 256 + col] = acc[mi][ni][r];
            }
        }
}

// ---------------------------------------------------------------------------
// K3: fused split-K reduce + noise + ReLU + MLP 256->128->64->10 + log_softmax
// 8 rows/block, 512 blocks.
// ---------------------------------------------------------------------------
__global__ __launch_bounds__(256) void k_mlp(
    const float* __restrict__ P, // (8,4096,256)
    const float* __restrict__ a_mat,  // (256,5,5)
    const float* __restrict__ noise,  // (256,5)
    const float* __restrict__ fc1_w, const float* __restrict__ fc1_b,
    const float* __restrict__ fc2_w, const float* __restrict__ fc2_b,
    const float* __restrict__ out_w, const float* __restrict__ out_b,
    float* __restrict__ out)     // (4096,10)
{
    __shared__ __align__(16) float Rt[8][260];
    __shared__ __align__(16) float H2[8][132];
    __shared__ __align__(16) float H3[8][68];
    __shared__ float LG[8][12];
    __shared__ float mrow[8], srow[8];
    __shared__ float nts[256];
    int t = threadIdx.x;
    int b0 = blockIdx.x * 8;

    // noise_term[j]
    {
        float nt = 0.f;
#pragma unroll
        for (int c = 0; c < 5; ++c) {
            float ar = 0.f;
#pragma unroll
            for (int m = 0; m < 5; ++m) ar += a_mat[t * 25 + c * 5 + m];
            nt += noise[t * 5 + c] * ar;
        }
        nts[t] = nt;
    }
    __syncthreads();

    // stage R rows: sum over 8 K-slices + noise + relu
    for (int i = t; i < 512; i += 256) {
        int r = i >> 6;
        int c4 = i & 63;
        size_t base = (size_t)(b0 + r) * 256 + c4 * 4;
        float4 sum = *(const float4*)&nts[c4 * 4];
#pragma unroll
        for (int ks = 0; ks < 8; ++ks) {
            float4 p = *(const float4*)(P + ((size_t)ks << 20) + base);
            sum.x += p.x; sum.y += p.y; sum.z += p.z; sum.w += p.w;
        }
        sum.x = fmaxf(sum.x, 0.f); sum.y = fmaxf(sum.y, 0.f);
        sum.z = fmaxf(sum.z, 0.f); sum.w = fmaxf(sum.w, 0.f);
        *(float4*)&Rt[r][c4 * 4] = sum;
    }
    __syncthreads();

    // fc1 + relu: 1024 outputs, 4/thread
    for (int i = t; i < 1024; i += 256) {
        int r = i & 7, o = i >> 3;
        float s = fc1_b[o];
        const float* wpt = fc1_w + o * 256;
        for (int c = 0; c < 256; c += 4) {
            float4 wv = *(const float4*)(wpt + c);
            float4 rv = *(const float4*)&Rt[r][c];
            s += rv.x * wv.x + rv.y * wv.y + rv.z * wv.z + rv.w * wv.w;
        }
        H2[r][o] = fmaxf(s, 0.f);
    }
    __syncthreads();

    // fc2 + relu
    for (int i = t; i < 512; i += 256) {
        int r = i & 7, o = i >> 3;
        float s = fc2_b[o];
        const float* wpt = fc2_w + o * 128;
        for (int c = 0; c < 128; c += 4) {
            float4 wv = *(const float4*)(wpt + c);
            float4 rv = *(const float4*)&H2[r][c];
            s += rv.x * wv.x + rv.y * wv.y + rv.z * wv.z + rv.w * wv.w;
        }
        H3[r][o] = fmaxf(s, 0.f);
    }
    __syncthreads();

    if (t < 80) {
        int r = t & 7, o = t >> 3;
        float s = out_b[o];
        const float* wpt = out_w + o * 64;
        for (int c = 0; c < 64; c += 4) {
            float4 wv = *(const float4*)(wpt + c);
            float4 rv = *(const float4*)&H3[r][c];
            s += rv.x * wv.x + rv.y * wv.y + rv.z * wv.z + rv.w * wv.w;
        }
        LG[r][o] = s;
    }
    __syncthreads();

    if (t < 8) {
        float m = -1e30f;
#pragma unroll
        for (int o = 0; o < 10; ++o) m = fmaxf(m, LG[t][o]);
        float s = 0.f;
#pragma unroll
        for (int o = 0; o < 10; ++o) s += expf(LG[t][o] - m);
        mrow[t] = m;
        srow[t] = logf(s);
    }
    __syncthreads();

    if (t < 80) {
        int r = t & 7, o = t >> 3;
        out[(size_t)(b0 + r) * 10 + o] = LG[r][o] - mrow[r] - srow[r];
    }
}

// ---------------------------------------------------------------------------
extern "C" void kernel_launch(void* const* d_in, const int* in_sizes, int n_in,
                              void* d_out, int out_size, void* d_ws, size_t ws_size,
                              hipStream_t stream)
{
    const float* x           = (const float*)d_in[0];
    const float* conv_w      = (const float*)d_in[1];
    const float* conv_b      = (const float*)d_in[2];
    const float* bn_gamma    = (const float*)d_in[3];
    const float* bn_beta     = (const float*)d_in[4];
    const float* bn_mean     = (const float*)d_in[5];
    const float* bn_var      = (const float*)d_in[6];
    const float* cut_w_big   = (const float*)d_in[7];
    const float* cut_w_small = (const float*)d_in[8];
    const float* fc1_w       = (const float*)d_in[9];
    const float* fc1_b       = (const float*)d_in[10];
    const float* fc2_w       = (const float*)d_in[11];
    const float* fc2_b       = (const float*)d_in[12];
    const float* out_w       = (const float*)d_in[13];
    const float* out_b       = (const float*)d_in[14];
    const float* b_mat       = (const float*)d_in[15];
    const float* h_mat       = (const float*)d_in[16];
    const float* a_mat       = (const float*)d_in[17];
    const float* indicator   = (const float*)d_in[18];
    const float* noise       = (const float*)d_in[19];
    float* out = (float*)d_out;

    char* ws = (char*)d_ws;
    short* Fbf = (short*)ws;                     // 32 MB
    short* Wbf = (short*)(ws + 33554432);        // 2 MB
    float* P   = (float*)(ws + 35651584);        // 32 MB (8 x 1M fp32)

    k_build_w<<<4096, 256, 0, stream>>>(cut_w_big, cut_w_small, b_mat, h_mat,
                                        a_mat, indicator, Wbf);
    k_branch<<<16384, 256, 0, stream>>>(x, conv_w, conv_b, bn_gamma, bn_beta,
                                        bn_mean, bn_var, Fbf);
    k_gemm<<<512, 256, 0, stream>>>(Fbf, Wbf, P);
    k_mlp<<<512, 256, 0, stream>>>(P, a_mat, noise, fc1_w, fc1_b, fc2_w, fc2_b,
                                   out_w, out_b, out);
}

// Round 4
// 385.280 us; speedup vs baseline: 1.3958x; 1.0984x over previous
//
#include <hip/hip_runtime.h>
#include <math.h>

typedef __attribute__((ext_vector_type(8))) short bf16x8;
typedef __attribute__((ext_vector_type(4))) float f32x4;

static __device__ __forceinline__ short f2bf(float f) {
    union { float f; unsigned u; } v; v.f = f;
    unsigned r = v.u + 0x7FFFu + ((v.u >> 16) & 1u);
    return (short)(r >> 16);
}

// ---------------------------------------------------------------------------
// Physical k-layout of F / W columns (4096), co packed innermost:
//   big n in {0,1}:   phys = n*1024 + pos*4 + co    (pos 0..255)
//   small n in {2..9}: phys = 2048 + (n-2)*256 + pos*4 + co (pos 0..63)
// ---------------------------------------------------------------------------

// K0: W_eff (bf16, 256 x 4096 phys-k) = cut_w * coeff[n(k), j]
__global__ __launch_bounds__(256) void k_build_w(
    const float* __restrict__ cut_w_big,   // (2,256,1024)
    const float* __restrict__ cut_w_small, // (8,256,256)
    const float* __restrict__ b_mat,       // (10,256)
    const float* __restrict__ h_mat,       // (10,64,5)
    const float* __restrict__ a_mat,       // (256,5,5)
    const float* __restrict__ indicator,   // (256,64)
    short* __restrict__ W)                 // (256,4096) bf16
{
    int bx = blockIdx.x;              // 4096 blocks
    int tid0 = bx << 8;
    int j = tid0 >> 12;               // block-uniform
    int kbase = tid0 & 4095;          // block-uniform
    int n = (kbase < 2048) ? (kbase >> 10) : 2 + ((kbase - 2048) >> 8);

    float arow[5];
#pragma unroll
    for (int c = 0; c < 5; ++c) {
        float s = 0.f;
#pragma unroll
        for (int m = 0; m < 5; ++m) s += a_mat[j * 25 + c * 5 + m];
        arow[c] = s;
    }
    int lane = threadIdx.x & 63;
    float hs = 0.f;
#pragma unroll
    for (int c = 0; c < 5; ++c) hs += h_mat[(n * 64 + lane) * 5 + c] * arow[c];
    float v = indicator[j * 64 + lane] * hs;
#pragma unroll
    for (int off = 32; off >= 1; off >>= 1) v += __shfl_xor(v, off);
    float coeff = b_mat[n * 256 + j] * v;

    int tid = tid0 + threadIdx.x;
    int k = tid & 4095;
    float w;
    if (k < 2048) {
        int nn = k >> 10;
        int r = k & 1023;
        int pos = r >> 2, co = r & 3;
        w = cut_w_big[((nn * 256 + j) << 10) + co * 256 + pos];
    } else {
        int kk2 = k - 2048;
        int nn = kk2 >> 8;
        int r = kk2 & 255;
        int pos = r >> 2, co = r & 3;
        w = cut_w_small[((nn * 256 + j) << 8) + co * 64 + pos];
    }
    W[tid] = f2bf(w * coeff);
}

// ---------------------------------------------------------------------------
// K1: conv3x3(pad1)+bias+BN+ReLU+pool2x2 -> F (4096x4096 bf16, phys-k)
// Even/odd column-plane LDS layout: window reads are lane-stride-1 pairs
// (ds_read2_b32-mergeable, conflict-free). Input col x: even x -> E[x/2],
// odd x -> O[(x+1)/2]. Window cols {2px-1..2px+2} = [O[px],E[px],O[px+1],E[px+1]].
// ---------------------------------------------------------------------------
__global__ __launch_bounds__(256) void k_branch(
    const float* __restrict__ x,      // (4096,3,64,64)
    const float* __restrict__ conv_w, // (10,4,3,3,3)
    const float* __restrict__ conv_b,
    const float* __restrict__ bn_g,
    const float* __restrict__ bn_b,
    const float* __restrict__ bn_m,
    const float* __restrict__ bn_v,
    short* __restrict__ F)            // (4096,4096) bf16
{
    // big:   per ci: E[34][18] + O[34][18] = 1224 floats, x3 = 3672
    // small: per page (ci*4+img, 12): E[18][10] + O[18][10] = 360, x12 = 4320
    __shared__ float in_s[4320];
    __shared__ float bn_a[4], bn_c[4];
    int t = threadIdx.x;
    int bx = blockIdx.x;

    if (bx < 8192) {
        // ---- big branch: 32x32 slice, 1 image/block ----
        int n = bx >> 12;
        int b = bx & 4095;
        int r0 = 32 * n;
        // halo zeroing: full rows 0 & 33 (both planes), side cols rows 1..32
        for (int i = t; i < 504; i += 256) {
            int addr;
            if (i < 216) {                 // 3ci x 2planes x 2rows x 18
                int ci = i / 72, rem = i % 72;
                int pl = rem / 36, rem2 = rem % 36;
                int row = (rem2 >= 18) ? 33 : 0;
                int col = rem2 % 18;
                addr = ci * 1224 + pl * 612 + row * 18 + col;
            } else {                       // 3ci x 32rows x {E16, O0, O17}
                int jx = i - 216;
                int ci = jx / 96, rem = jx % 96;
                int row = rem / 3 + 1, wh = rem % 3;
                addr = ci * 1224 + row * 18 +
                       (wh == 0 ? 16 : (wh == 1 ? 612 + 0 : 612 + 17));
            }
            in_s[addr] = 0.f;
        }
        // stage interior rows 1..32: 768 float4 (3/thread)
        for (int i = t; i < 768; i += 256) {
            int ci = i >> 8, rem = i & 255, yy = rem >> 3, xq = rem & 7;
            float4 v = *(const float4*)(x + ((size_t)(b * 3 + ci) * 64 + r0 + yy) * 64 + xq * 4);
            int eb = ci * 1224 + (yy + 1) * 18;
            int ob = eb + 612;
            *(float2*)&in_s[eb + 2 * xq] = make_float2(v.x, v.z);   // E[2xq],E[2xq+1]
            in_s[ob + 2 * xq + 1] = v.y;                            // O[2xq+1] (col 4xq+1)
            in_s[ob + 2 * xq + 2] = v.w;                            // O[2xq+2] (col 4xq+3)
        }
        if (t < 4) {
            float scale = bn_g[n * 4 + t] * rsqrtf(bn_v[n * 4 + t] + 1e-5f);
            bn_a[t] = scale;
            bn_c[t] = (conv_b[n * 4 + t] - bn_m[n * 4 + t]) * scale + bn_b[n * 4 + t];
        }
        __syncthreads();

        int py = t >> 4, px = t & 15;
        float s[4][4];
#pragma unroll
        for (int a = 0; a < 4; ++a)
#pragma unroll
            for (int p = 0; p < 4; ++p) s[a][p] = 0.f;
        const float* wp = conv_w + n * 108;
#pragma unroll
        for (int ci = 0; ci < 3; ++ci) {
            float wv[16];
#pragma unroll
            for (int dy = 0; dy < 4; ++dy) {
                int rowb = ci * 1224 + (2 * py + dy) * 18 + px;
                float e0 = in_s[rowb];            // col 2px
                float e1 = in_s[rowb + 1];        // col 2px+2
                float o0 = in_s[rowb + 612];      // col 2px-1
                float o1 = in_s[rowb + 613];      // col 2px+1
                wv[dy * 4 + 0] = o0; wv[dy * 4 + 1] = e0;
                wv[dy * 4 + 2] = o1; wv[dy * 4 + 3] = e1;
            }
#pragma unroll
            for (int co = 0; co < 4; ++co) {
                const float* kk = wp + co * 27 + ci * 9;
                float k0 = kk[0], k1 = kk[1], k2 = kk[2], k3 = kk[3], k4 = kk[4],
                      k5 = kk[5], k6 = kk[6], k7 = kk[7], k8 = kk[8];
                s[co][0] += wv[0] * k0 + wv[1] * k1 + wv[2] * k2 + wv[4] * k3 + wv[5] * k4 + wv[6] * k5 + wv[8] * k6 + wv[9] * k7 + wv[10] * k8;
                s[co][1] += wv[1] * k0 + wv[2] * k1 + wv[3] * k2 + wv[5] * k3 + wv[6] * k4 + wv[7] * k5 + wv[9] * k6 + wv[10] * k7 + wv[11] * k8;
                s[co][2] += wv[4] * k0 + wv[5] * k1 + wv[6] * k2 + wv[8] * k3 + wv[9] * k4 + wv[10] * k5 + wv[12] * k6 + wv[13] * k7 + wv[14] * k8;
                s[co][3] += wv[5] * k0 + wv[6] * k1 + wv[7] * k2 + wv[9] * k3 + wv[10] * k4 + wv[11] * k5 + wv[13] * k6 + wv[14] * k7 + wv[15] * k8;
            }
        }
        short4 pk;
        {
            float m[4];
#pragma unroll
            for (int co = 0; co < 4; ++co) {
                float a = bn_a[co], c2 = bn_c[co];
                float v0 = fmaxf(s[co][0] * a + c2, 0.f);
                float v1 = fmaxf(s[co][1] * a + c2, 0.f);
                float v2 = fmaxf(s[co][2] * a + c2, 0.f);
                float v3 = fmaxf(s[co][3] * a + c2, 0.f);
                m[co] = fmaxf(fmaxf(v0, v1), fmaxf(v2, v3));
            }
            pk.x = f2bf(m[0]); pk.y = f2bf(m[1]); pk.z = f2bf(m[2]); pk.w = f2bf(m[3]);
        }
        *(short4*)&F[(size_t)b * 4096 + n * 1024 + t * 4] = pk;
    } else {
        // ---- small branches: 16x16 slices, 4 images/block ----
        int i2 = bx - 8192;
        int n = 2 + (i2 >> 10);
        int g = i2 & 1023;
        int b0 = g * 4;
        int r0 = 16 * ((n - 2) & 3);
        int c0 = 32 + 16 * ((n - 2) >> 2);
        // halo: full rows 0 & 17 both planes (480), sides rows 1..16 {E8, O0} (384)
        for (int i = t; i < 864; i += 256) {
            int addr;
            if (i < 480) {                 // 12 pages x 2 planes x 2 rows x 10
                int page = i / 40, rem = i % 40;
                int pl = rem / 20, rem2 = rem % 20;
                int row = (rem2 >= 10) ? 17 : 0;
                int col = rem2 % 10;
                addr = page * 360 + pl * 180 + row * 10 + col;
            } else {
                int jx = i - 480;          // 12 pages x 16 rows x 2
                int page = jx / 32, rem = jx % 32;
                int row = (rem >> 1) + 1, wh = rem & 1;
                addr = page * 360 + row * 10 + (wh ? 180 + 0 : 8);
            }
            in_s[addr] = 0.f;
        }
        // stage interior: 768 float4 (3/thread), page = ci*4+img
        for (int i = t; i < 768; i += 256) {
            int page = i >> 6, rem = i & 63, yy = rem >> 2, xq = rem & 3;
            int ci = page >> 2, img = page & 3;
            float4 v = *(const float4*)(x + ((size_t)((b0 + img) * 3 + ci) * 64 + r0 + yy) * 64 + c0 + xq * 4);
            int eb = page * 360 + (yy + 1) * 10;
            int ob = eb + 180;
            *(float2*)&in_s[eb + 2 * xq] = make_float2(v.x, v.z);
            in_s[ob + 2 * xq + 1] = v.y;
            in_s[ob + 2 * xq + 2] = v.w;
        }
        if (t < 4) {
            float scale = bn_g[n * 4 + t] * rsqrtf(bn_v[n * 4 + t] + 1e-5f);
            bn_a[t] = scale;
            bn_c[t] = (conv_b[n * 4 + t] - bn_m[n * 4 + t]) * scale + bn_b[n * 4 + t];
        }
        __syncthreads();

        int img = t >> 6;
        int pos = t & 63;
        int py = pos >> 3, px = pos & 7;
        float s[4][4];
#pragma unroll
        for (int a = 0; a < 4; ++a)
#pragma unroll
            for (int p = 0; p < 4; ++p) s[a][p] = 0.f;
        const float* wp = conv_w + n * 108;
#pragma unroll
        for (int ci = 0; ci < 3; ++ci) {
            float wv[16];
            int pageb = (ci * 4 + img) * 360;
#pragma unroll
            for (int dy = 0; dy < 4; ++dy) {
                int rowb = pageb + (2 * py + dy) * 10 + px;
                float e0 = in_s[rowb];
                float e1 = in_s[rowb + 1];
                float o0 = in_s[rowb + 180];
                float o1 = in_s[rowb + 181];
                wv[dy * 4 + 0] = o0; wv[dy * 4 + 1] = e0;
                wv[dy * 4 + 2] = o1; wv[dy * 4 + 3] = e1;
            }
#pragma unroll
            for (int co = 0; co < 4; ++co) {
                const float* kk = wp + co * 27 + ci * 9;
                float k0 = kk[0], k1 = kk[1], k2 = kk[2], k3 = kk[3], k4 = kk[4],
                      k5 = kk[5], k6 = kk[6], k7 = kk[7], k8 = kk[8];
                s[co][0] += wv[0] * k0 + wv[1] * k1 + wv[2] * k2 + wv[4] * k3 + wv[5] * k4 + wv[6] * k5 + wv[8] * k6 + wv[9] * k7 + wv[10] * k8;
                s[co][1] += wv[1] * k0 + wv[2] * k1 + wv[3] * k2 + wv[5] * k3 + wv[6] * k4 + wv[7] * k5 + wv[9] * k6 + wv[10] * k7 + wv[11] * k8;
                s[co][2] += wv[4] * k0 + wv[5] * k1 + wv[6] * k2 + wv[8] * k3 + wv[9] * k4 + wv[10] * k5 + wv[12] * k6 + wv[13] * k7 + wv[14] * k8;
                s[co][3] += wv[5] * k0 + wv[6] * k1 + wv[7] * k2 + wv[9] * k3 + wv[10] * k4 + wv[11] * k5 + wv[13] * k6 + wv[14] * k7 + wv[15] * k8;
            }
        }
        short4 pk;
        {
            float m[4];
#pragma unroll
            for (int co = 0; co < 4; ++co) {
                float a = bn_a[co], c2 = bn_c[co];
                float v0 = fmaxf(s[co][0] * a + c2, 0.f);
                float v1 = fmaxf(s[co][1] * a + c2, 0.f);
                float v2 = fmaxf(s[co][2] * a + c2, 0.f);
                float v3 = fmaxf(s[co][3] * a + c2, 0.f);
                m[co] = fmaxf(fmaxf(v0, v1), fmaxf(v2, v3));
            }
            pk.x = f2bf(m[0]); pk.y = f2bf(m[1]); pk.z = f2bf(m[2]); pk.w = f2bf(m[3]);
        }
        *(short4*)&F[(size_t)(b0 + img) * 4096 + 2048 + (n - 2) * 256 + pos * 4] = pk;
    }
}

// ---------------------------------------------------------------------------
// K2: bf16 MFMA GEMM, split-K=8 (unchanged)
// ---------------------------------------------------------------------------
__global__ __launch_bounds__(256) void k_gemm(
    const short* __restrict__ F, // (4096,4096) bf16
    const short* __restrict__ W, // (256,4096) bf16
    float* __restrict__ P)       // (8,4096,256)
{
    __shared__ short As[128 * 64];
    __shared__ short Bs[128 * 64];
    int bx = blockIdx.x;          // 512 = 32 mtiles x 2 jtiles x 8 ksplit
    int mt = bx & 31;
    int jt = (bx >> 5) & 1;
    int ks = bx >> 6;
    int t = threadIdx.x;
    int m0 = mt << 7, j0 = jt << 7;

    int lane = t & 63;
    int wave = t >> 6;
    int wm = wave & 1, wn = wave >> 1;
    int l16 = lane & 15, quad = lane >> 4;

    f32x4 acc[4][4];
#pragma unroll
    for (int i = 0; i < 4; ++i)
#pragma unroll
        for (int j = 0; j < 4; ++j) acc[i][j] = (f32x4){0.f, 0.f, 0.f, 0.f};

    for (int it = 0; it < 8; ++it) {
        int k0 = (ks << 9) + (it << 6);
#pragma unroll
        for (int r = 0; r < 4; ++r) {
            int c = (r << 8) + t;
            int row = c >> 3, sgl = c & 7;
            int gsw = sgl ^ (row & 7);
            const short* gpA = F + ((size_t)(m0 + row) << 12) + k0 + (gsw << 3);
            const short* gpB = W + ((size_t)(j0 + row) << 12) + k0 + (gsw << 3);
            __builtin_amdgcn_global_load_lds(
                (const __attribute__((address_space(1))) void*)gpA,
                (__attribute__((address_space(3))) void*)(As + (c << 3)), 16, 0, 0);
            __builtin_amdgcn_global_load_lds(
                (const __attribute__((address_space(1))) void*)gpB,
                (__attribute__((address_space(3))) void*)(Bs + (c << 3)), 16, 0, 0);
        }
        __syncthreads();
#pragma unroll
        for (int ks2 = 0; ks2 < 2; ++ks2) {
            bf16x8 af[4], bfr[4];
#pragma unroll
            for (int mi = 0; mi < 4; ++mi) {
                int row = (wm << 6) + (mi << 4) + l16;
                int q = (ks2 << 2) + quad;
                int sl = q ^ (row & 7);
                af[mi] = *(const bf16x8*)&As[(row << 6) + (sl << 3)];
            }
#pragma unroll
            for (int ni = 0; ni < 4; ++ni) {
                int row = (wn << 6) + (ni << 4) + l16;
                int q = (ks2 << 2) + quad;
                int sl = q ^ (row & 7);
                bfr[ni] = *(const bf16x8*)&Bs[(row << 6) + (sl << 3)];
            }
#pragma unroll
            for (int mi = 0; mi < 4; ++mi)
#pragma unroll
                for (int ni = 0; ni < 4; ++ni)
                    acc[mi][ni] = __builtin_amdgcn_mfma_f32_16x16x32_bf16(
                        af[mi], bfr[ni], acc[mi][ni], 0, 0, 0);
        }
        __syncthreads();
    }

    float* Pp = P + ((size_t)ks << 20);
#pragma unroll
    for (int mi = 0; mi < 4; ++mi)
#pragma unroll
        for (int ni = 0; ni < 4; ++ni) {
            int col = j0 + (wn << 6) + (ni << 4) + l16;
#pragma unroll
            for (int r = 0; r < 4; ++r) {
                int row = m0 + (wm << 6) + (mi << 4) + (quad << 2) + r;
                Pp[(size_t)row * 256 + col] = acc[mi][ni][r];
            }
        }
}

// ---------------------------------------------------------------------------
// K3: fused split-K reduce + noise + ReLU + MLP + log_softmax.
// 8 rows/block, 512 blocks. Weight-stationary threads: thread owns an output
// column x K-slice; weight fetched once/block, rows read via LDS broadcast.
// ---------------------------------------------------------------------------
__global__ __launch_bounds__(256) void k_mlp(
    const float* __restrict__ P,      // (8,4096,256)
    const float* __restrict__ a_mat,  // (256,5,5)
    const float* __restrict__ noise,  // (256,5)
    const float* __restrict__ fc1_w, const float* __restrict__ fc1_b,
    const float* __restrict__ fc2_w, const float* __restrict__ fc2_b,
    const float* __restrict__ out_w, const float* __restrict__ out_b,
    float* __restrict__ out)          // (4096,10)
{
    __shared__ __align__(16) float Rt[8][260];
    __shared__ float P1[2][8][132];
    __shared__ __align__(16) float H2[8][132];
    __shared__ float P2[4][8][68];
    __shared__ __align__(16) float H3[8][68];
    __shared__ float LG[8][12];
    __shared__ float mrow[8], srow[8];
    __shared__ float nts[256];
    int t = threadIdx.x;
    int b0 = blockIdx.x * 8;

    // noise_term[j]
    {
        float nt = 0.f;
#pragma unroll
        for (int c = 0; c < 5; ++c) {
            float ar = 0.f;
#pragma unroll
            for (int m = 0; m < 5; ++m) ar += a_mat[t * 25 + c * 5 + m];
            nt += noise[t * 5 + c] * ar;
        }
        nts[t] = nt;
    }
    __syncthreads();

    // stage R rows: sum over 8 K-slices + noise + relu
    for (int i = t; i < 512; i += 256) {
        int r = i >> 6;
        int c4 = i & 63;
        size_t base = (size_t)(b0 + r) * 256 + c4 * 4;
        float4 sum = *(const float4*)&nts[c4 * 4];
#pragma unroll
        for (int ks = 0; ks < 8; ++ks) {
            float4 p = *(const float4*)(P + ((size_t)ks << 20) + base);
            sum.x += p.x; sum.y += p.y; sum.z += p.z; sum.w += p.w;
        }
        sum.x = fmaxf(sum.x, 0.f); sum.y = fmaxf(sum.y, 0.f);
        sum.z = fmaxf(sum.z, 0.f); sum.w = fmaxf(sum.w, 0.f);
        *(float4*)&Rt[r][c4 * 4] = sum;
    }
    __syncthreads();

    // fc1 partials: o = t&127, half = t>>7 (K-half of 128)
    {
        int o = t & 127, h = t >> 7;
        float acc[8];
#pragma unroll
        for (int r = 0; r < 8; ++r) acc[r] = 0.f;
        const float* wr = fc1_w + o * 256 + h * 128;
        for (int c = 0; c < 128; c += 4) {
            float4 wv = *(const float4*)(wr + c);
#pragma unroll
            for (int r = 0; r < 8; ++r) {
                float4 rv = *(const float4*)&Rt[r][h * 128 + c];
                acc[r] += rv.x * wv.x + rv.y * wv.y + rv.z * wv.z + rv.w * wv.w;
            }
        }
#pragma unroll
        for (int r = 0; r < 8; ++r) P1[h][r][o] = acc[r];
    }
    __syncthreads();

    // combine fc1 halves + bias + relu: 1024 tasks
    for (int i = t; i < 1024; i += 256) {
        int r = i >> 7, o = i & 127;
        H2[r][o] = fmaxf(P1[0][r][o] + P1[1][r][o] + fc1_b[o], 0.f);
    }
    __syncthreads();

    // fc2 partials: o = t&63, q = t>>6 (K-quarter of 32)
    {
        int o = t & 63, q = t >> 6;
        float acc[8];
#pragma unroll
        for (int r = 0; r < 8; ++r) acc[r] = 0.f;
        const float* wr = fc2_w + o * 128 + q * 32;
        for (int c = 0; c < 32; c += 4) {
            float4 wv = *(const float4*)(wr + c);
#pragma unroll
            for (int r = 0; r < 8; ++r) {
                float4 rv = *(const float4*)&H2[r][q * 32 + c];
                acc[r] += rv.x * wv.x + rv.y * wv.y + rv.z * wv.z + rv.w * wv.w;
            }
        }
#pragma unroll
        for (int r = 0; r < 8; ++r) P2[q][r][o] = acc[r];
    }
    __syncthreads();

    // combine fc2 quarters + bias + relu: 512 tasks
    for (int i = t; i < 512; i += 256) {
        int r = i >> 6, o = i & 63;
        H3[r][o] = fmaxf(P2[0][r][o] + P2[1][r][o] + P2[2][r][o] + P2[3][r][o]
                         + fc2_b[o], 0.f);
    }
    __syncthreads();

    // out layer: 80 tasks
    if (t < 80) {
        int r = t & 7, o = t >> 3;
        float s = out_b[o];
        const float* wpt = out_w + o * 64;
        for (int c = 0; c < 64; c += 4) {
            float4 wv = *(const float4*)(wpt + c);
            float4 rv = *(const float4*)&H3[r][c];
            s += rv.x * wv.x + rv.y * wv.y + rv.z * wv.z + rv.w * wv.w;
        }
        LG[r][o] = s;
    }
    __syncthreads();

    if (t < 8) {
        float m = -1e30f;
#pragma unroll
        for (int o = 0; o < 10; ++o) m = fmaxf(m, LG[t][o]);
        float s = 0.f;
#pragma unroll
        for (int o = 0; o < 10; ++o) s += expf(LG[t][o] - m);
        mrow[t] = m;
        srow[t] = logf(s);
    }
    __syncthreads();

    if (t < 80) {
        int r = t & 7, o = t >> 3;
        out[(size_t)(b0 + r) * 10 + o] = LG[r][o] - mrow[r] - srow[r];
    }
}

// ---------------------------------------------------------------------------
extern "C" void kernel_launch(void* const* d_in, const int* in_sizes, int n_in,
                              void* d_out, int out_size, void* d_ws, size_t ws_size,
                              hipStream_t stream)
{
    const float* x           = (const float*)d_in[0];
    const float* conv_w      = (const float*)d_in[1];
    const float* conv_b      = (const float*)d_in[2];
    const float* bn_gamma    = (const float*)d_in[3];
    const float* bn_beta     = (const float*)d_in[4];
    const float* bn_mean     = (const float*)d_in[5];
    const float* bn_var      = (const float*)d_in[6];
    const float* cut_w_big   = (const float*)d_in[7];
    const float* cut_w_small = (const float*)d_in[8];
    const float* fc1_w       = (const float*)d_in[9];
    const float* fc1_b       = (const float*)d_in[10];
    const float* fc2_w       = (const float*)d_in[11];
    const float* fc2_b       = (const float*)d_in[12];
    const float* out_w       = (const float*)d_in[13];
    const float* out_b       = (const float*)d_in[14];
    const float* b_mat       = (const float*)d_in[15];
    const float* h_mat       = (const float*)d_in[16];
    const float* a_mat       = (const float*)d_in[17];
    const float* indicator   = (const float*)d_in[18];
    const float* noise       = (const float*)d_in[19];
    float* out = (float*)d_out;

    char* ws = (char*)d_ws;
    short* Fbf = (short*)ws;                     // 32 MB
    short* Wbf = (short*)(ws + 33554432);        // 2 MB
    float* P   = (float*)(ws + 35651584);        // 32 MB (8 x 1M fp32)

    k_build_w<<<4096, 256, 0, stream>>>(cut_w_big, cut_w_small, b_mat, h_mat,
                                        a_mat, indicator, Wbf);
    k_branch<<<16384, 256, 0, stream>>>(x, conv_w, conv_b, bn_gamma, bn_beta,
                                        bn_mean, bn_var, Fbf);
    k_gemm<<<512, 256, 0, stream>>>(Fbf, Wbf, P);
    k_mlp<<<512, 256, 0, stream>>>(P, a_mat, noise, fc1_w, fc1_b, fc2_w, fc2_b,
                                   out_w, out_b, out);
}

// Round 5
// 377.565 us; speedup vs baseline: 1.4243x; 1.0204x over previous
//
#include <hip/hip_runtime.h>
#include <math.h>

typedef __attribute__((ext_vector_type(8))) short bf16x8;
typedef __attribute__((ext_vector_type(4))) float f32x4;

static __device__ __forceinline__ short f2bf(float f) {
    union { float f; unsigned u; } v; v.f = f;
    unsigned r = v.u + 0x7FFFu + ((v.u >> 16) & 1u);
    return (short)(r >> 16);
}

// ---------------------------------------------------------------------------
// Physical k-layout of F / W columns (4096), co packed innermost:
//   big n in {0,1}:   phys = n*1024 + pos*4 + co    (pos 0..255)
//   small n in {2..9}: phys = 2048 + (n-2)*256 + pos*4 + co (pos 0..63)
// ---------------------------------------------------------------------------

// K0: W_eff (bf16, 256 x 4096 phys-k) = cut_w * coeff[n(k), j]
__global__ __launch_bounds__(256) void k_build_w(
    const float* __restrict__ cut_w_big,   // (2,256,1024)
    const float* __restrict__ cut_w_small, // (8,256,256)
    const float* __restrict__ b_mat,       // (10,256)
    const float* __restrict__ h_mat,       // (10,64,5)
    const float* __restrict__ a_mat,       // (256,5,5)
    const float* __restrict__ indicator,   // (256,64)
    short* __restrict__ W)                 // (256,4096) bf16
{
    int bx = blockIdx.x;              // 4096 blocks
    int tid0 = bx << 8;
    int j = tid0 >> 12;               // block-uniform
    int kbase = tid0 & 4095;          // block-uniform
    int n = (kbase < 2048) ? (kbase >> 10) : 2 + ((kbase - 2048) >> 8);

    float arow[5];
#pragma unroll
    for (int c = 0; c < 5; ++c) {
        float s = 0.f;
#pragma unroll
        for (int m = 0; m < 5; ++m) s += a_mat[j * 25 + c * 5 + m];
        arow[c] = s;
    }
    int lane = threadIdx.x & 63;
    float hs = 0.f;
#pragma unroll
    for (int c = 0; c < 5; ++c) hs += h_mat[(n * 64 + lane) * 5 + c] * arow[c];
    float v = indicator[j * 64 + lane] * hs;
#pragma unroll
    for (int off = 32; off >= 1; off >>= 1) v += __shfl_xor(v, off);
    float coeff = b_mat[n * 256 + j] * v;

    int tid = tid0 + threadIdx.x;
    int k = tid & 4095;
    float w;
    if (k < 2048) {
        int nn = k >> 10;
        int r = k & 1023;
        int pos = r >> 2, co = r & 3;
        w = cut_w_big[((nn * 256 + j) << 10) + co * 256 + pos];
    } else {
        int kk2 = k - 2048;
        int nn = kk2 >> 8;
        int r = kk2 & 255;
        int pos = r >> 2, co = r & 3;
        w = cut_w_small[((nn * 256 + j) << 8) + co * 64 + pos];
    }
    W[tid] = f2bf(w * coeff);
}

// ---------------------------------------------------------------------------
// K1: conv3x3(pad1)+bias+BN+ReLU+pool2x2 -> F (4096x4096 bf16, phys-k)
// Even/odd column planes with CONFLICT-FREE row pitch:
//   big:   pitch 24 -> lane bank = (48*py + px) mod 32 = 16*py+px -> 2-way (free)
//   small: pitch 12 -> 24*py mod 32 cycles {0,24,16,8} -> 2-way (free)
// Full-tile float4 zero replaces divmod-heavy halo addressing.
// ---------------------------------------------------------------------------
__global__ __launch_bounds__(256) void k_branch(
    const float* __restrict__ x,      // (4096,3,64,64)
    const float* __restrict__ conv_w, // (10,4,3,3,3)
    const float* __restrict__ conv_b,
    const float* __restrict__ bn_g,
    const float* __restrict__ bn_b,
    const float* __restrict__ bn_m,
    const float* __restrict__ bn_v,
    short* __restrict__ F)            // (4096,4096) bf16
{
    // big:   per ci: E[34][24] + O[34][24] = 1632 floats, x3 = 4896
    // small: per page (ci*4+img): E[18][12]+O[18][12] = 432, x12 = 5184
    __shared__ __align__(16) float in_s[5184];
    __shared__ float bn_a[4], bn_c[4];
    int t = threadIdx.x;
    int bx = blockIdx.x;

    if (bx < 8192) {
        // ---- big branch: 32x32 slice, 1 image/block ----
        int n = bx >> 12;
        int b = bx & 4095;
        int r0 = 32 * n;
        // full-tile zero (4896 floats = 1224 float4)
        {
            float4 z4 = make_float4(0.f, 0.f, 0.f, 0.f);
            float4* zp = (float4*)in_s;
            for (int i = t; i < 1224; i += 256) zp[i] = z4;
        }
        if (t < 4) {
            float scale = bn_g[n * 4 + t] * rsqrtf(bn_v[n * 4 + t] + 1e-5f);
            bn_a[t] = scale;
            bn_c[t] = (conv_b[n * 4 + t] - bn_m[n * 4 + t]) * scale + bn_b[n * 4 + t];
        }
        __syncthreads();
        // stage interior rows 1..32: 768 float4 (3/thread)
        for (int i = t; i < 768; i += 256) {
            int ci = i >> 8, rem = i & 255, yy = rem >> 3, xq = rem & 7;
            float4 v = *(const float4*)(x + ((size_t)(b * 3 + ci) * 64 + r0 + yy) * 64 + xq * 4);
            int eb = ci * 1632 + (yy + 1) * 24;
            int ob = eb + 816;
            *(float2*)&in_s[eb + 2 * xq] = make_float2(v.x, v.z);   // E[2xq],E[2xq+1]
            in_s[ob + 2 * xq + 1] = v.y;                            // O: col 4xq+1
            in_s[ob + 2 * xq + 2] = v.w;                            // O: col 4xq+3
        }
        __syncthreads();

        int py = t >> 4, px = t & 15;
        float s[4][4];
#pragma unroll
        for (int a = 0; a < 4; ++a)
#pragma unroll
            for (int p = 0; p < 4; ++p) s[a][p] = 0.f;
        const float* wp = conv_w + n * 108;
#pragma unroll
        for (int ci = 0; ci < 3; ++ci) {
            float wv[16];
#pragma unroll
            for (int dy = 0; dy < 4; ++dy) {
                int rowb = ci * 1632 + (2 * py + dy) * 24 + px;
                float e0 = in_s[rowb];            // col 2px
                float e1 = in_s[rowb + 1];        // col 2px+2
                float o0 = in_s[rowb + 816];      // col 2px-1
                float o1 = in_s[rowb + 817];      // col 2px+1
                wv[dy * 4 + 0] = o0; wv[dy * 4 + 1] = e0;
                wv[dy * 4 + 2] = o1; wv[dy * 4 + 3] = e1;
            }
#pragma unroll
            for (int co = 0; co < 4; ++co) {
                const float* kk = wp + co * 27 + ci * 9;
                float k0 = kk[0], k1 = kk[1], k2 = kk[2], k3 = kk[3], k4 = kk[4],
                      k5 = kk[5], k6 = kk[6], k7 = kk[7], k8 = kk[8];
                s[co][0] += wv[0] * k0 + wv[1] * k1 + wv[2] * k2 + wv[4] * k3 + wv[5] * k4 + wv[6] * k5 + wv[8] * k6 + wv[9] * k7 + wv[10] * k8;
                s[co][1] += wv[1] * k0 + wv[2] * k1 + wv[3] * k2 + wv[5] * k3 + wv[6] * k4 + wv[7] * k5 + wv[9] * k6 + wv[10] * k7 + wv[11] * k8;
                s[co][2] += wv[4] * k0 + wv[5] * k1 + wv[6] * k2 + wv[8] * k3 + wv[9] * k4 + wv[10] * k5 + wv[12] * k6 + wv[13] * k7 + wv[14] * k8;
                s[co][3] += wv[5] * k0 + wv[6] * k1 + wv[7] * k2 + wv[9] * k3 + wv[10] * k4 + wv[11] * k5 + wv[13] * k6 + wv[14] * k7 + wv[15] * k8;
            }
        }
        short4 pk;
        {
            float m[4];
#pragma unroll
            for (int co = 0; co < 4; ++co) {
                float a = bn_a[co], c2 = bn_c[co];
                float v0 = fmaxf(s[co][0] * a + c2, 0.f);
                float v1 = fmaxf(s[co][1] * a + c2, 0.f);
                float v2 = fmaxf(s[co][2] * a + c2, 0.f);
                float v3 = fmaxf(s[co][3] * a + c2, 0.f);
                m[co] = fmaxf(fmaxf(v0, v1), fmaxf(v2, v3));
            }
            pk.x = f2bf(m[0]); pk.y = f2bf(m[1]); pk.z = f2bf(m[2]); pk.w = f2bf(m[3]);
        }
        *(short4*)&F[(size_t)b * 4096 + n * 1024 + t * 4] = pk;
    } else {
        // ---- small branches: 16x16 slices, 4 images/block ----
        int i2 = bx - 8192;
        int n = 2 + (i2 >> 10);
        int g = i2 & 1023;
        int b0 = g * 4;
        int r0 = 16 * ((n - 2) & 3);
        int c0 = 32 + 16 * ((n - 2) >> 2);
        // full-tile zero (5184 floats = 1296 float4)
        {
            float4 z4 = make_float4(0.f, 0.f, 0.f, 0.f);
            float4* zp = (float4*)in_s;
            for (int i = t; i < 1296; i += 256) zp[i] = z4;
        }
        if (t < 4) {
            float scale = bn_g[n * 4 + t] * rsqrtf(bn_v[n * 4 + t] + 1e-5f);
            bn_a[t] = scale;
            bn_c[t] = (conv_b[n * 4 + t] - bn_m[n * 4 + t]) * scale + bn_b[n * 4 + t];
        }
        __syncthreads();
        // stage interior: 768 float4 (3/thread), page = ci*4+img
        for (int i = t; i < 768; i += 256) {
            int page = i >> 6, rem = i & 63, yy = rem >> 2, xq = rem & 3;
            int ci = page >> 2, img = page & 3;
            float4 v = *(const float4*)(x + ((size_t)((b0 + img) * 3 + ci) * 64 + r0 + yy) * 64 + c0 + xq * 4);
            int eb = page * 432 + (yy + 1) * 12;
            int ob = eb + 216;
            *(float2*)&in_s[eb + 2 * xq] = make_float2(v.x, v.z);
            in_s[ob + 2 * xq + 1] = v.y;
            in_s[ob + 2 * xq + 2] = v.w;
        }
        __syncthreads();

        int img = t >> 6;
        int pos = t & 63;
        int py = pos >> 3, px = pos & 7;
        float s[4][4];
#pragma unroll
        for (int a = 0; a < 4; ++a)
#pragma unroll
            for (int p = 0; p < 4; ++p) s[a][p] = 0.f;
        const float* wp = conv_w + n * 108;
#pragma unroll
        for (int ci = 0; ci < 3; ++ci) {
            float wv[16];
            int pageb = (ci * 4 + img) * 432;
#pragma unroll
            for (int dy = 0; dy < 4; ++dy) {
                int rowb = pageb + (2 * py + dy) * 12 + px;
                float e0 = in_s[rowb];
                float e1 = in_s[rowb + 1];
                float o0 = in_s[rowb + 216];
                float o1 = in_s[rowb + 217];
                wv[dy * 4 + 0] = o0; wv[dy * 4 + 1] = e0;
                wv[dy * 4 + 2] = o1; wv[dy * 4 + 3] = e1;
            }
#pragma unroll
            for (int co = 0; co < 4; ++co) {
                const float* kk = wp + co * 27 + ci * 9;
                float k0 = kk[0], k1 = kk[1], k2 = kk[2], k3 = kk[3], k4 = kk[4],
                      k5 = kk[5], k6 = kk[6], k7 = kk[7], k8 = kk[8];
                s[co][0] += wv[0] * k0 + wv[1] * k1 + wv[2] * k2 + wv[4] * k3 + wv[5] * k4 + wv[6] * k5 + wv[8] * k6 + wv[9] * k7 + wv[10] * k8;
                s[co][1] += wv[1] * k0 + wv[2] * k1 + wv[3] * k2 + wv[5] * k3 + wv[6] * k4 + wv[7] * k5 + wv[9] * k6 + wv[10] * k7 + wv[11] * k8;
                s[co][2] += wv[4] * k0 + wv[5] * k1 + wv[6] * k2 + wv[8] * k3 + wv[9] * k4 + wv[10] * k5 + wv[12] * k6 + wv[13] * k7 + wv[14] * k8;
                s[co][3] += wv[5] * k0 + wv[6] * k1 + wv[7] * k2 + wv[9] * k3 + wv[10] * k4 + wv[11] * k5 + wv[13] * k6 + wv[14] * k7 + wv[15] * k8;
            }
        }
        short4 pk;
        {
            float m[4];
#pragma unroll
            for (int co = 0; co < 4; ++co) {
                float a = bn_a[co], c2 = bn_c[co];
                float v0 = fmaxf(s[co][0] * a + c2, 0.f);
                float v1 = fmaxf(s[co][1] * a + c2, 0.f);
                float v2 = fmaxf(s[co][2] * a + c2, 0.f);
                float v3 = fmaxf(s[co][3] * a + c2, 0.f);
                m[co] = fmaxf(fmaxf(v0, v1), fmaxf(v2, v3));
            }
            pk.x = f2bf(m[0]); pk.y = f2bf(m[1]); pk.z = f2bf(m[2]); pk.w = f2bf(m[3]);
        }
        *(short4*)&F[(size_t)(b0 + img) * 4096 + 2048 + (n - 2) * 256 + pos * 4] = pk;
    }
}

// ---------------------------------------------------------------------------
// K2: bf16 MFMA GEMM, split-K=8 (unchanged)
// ---------------------------------------------------------------------------
__global__ __launch_bounds__(256) void k_gemm(
    const short* __restrict__ F, // (4096,4096) bf16
    const short* __restrict__ W, // (256,4096) bf16
    float* __restrict__ P)       // (8,4096,256)
{
    __shared__ short As[128 * 64];
    __shared__ short Bs[128 * 64];
    int bx = blockIdx.x;          // 512 = 32 mtiles x 2 jtiles x 8 ksplit
    int mt = bx & 31;
    int jt = (bx >> 5) & 1;
    int ks = bx >> 6;
    int t = threadIdx.x;
    int m0 = mt << 7, j0 = jt << 7;

    int lane = t & 63;
    int wave = t >> 6;
    int wm = wave & 1, wn = wave >> 1;
    int l16 = lane & 15, quad = lane >> 4;

    f32x4 acc[4][4];
#pragma unroll
    for (int i = 0; i < 4; ++i)
#pragma unroll
        for (int j = 0; j < 4; ++j) acc[i][j] = (f32x4){0.f, 0.f, 0.f, 0.f};

    for (int it = 0; it < 8; ++it) {
        int k0 = (ks << 9) + (it << 6);
#pragma unroll
        for (int r = 0; r < 4; ++r) {
            int c = (r << 8) + t;
            int row = c >> 3, sgl = c & 7;
            int gsw = sgl ^ (row & 7);
            const short* gpA = F + ((size_t)(m0 + row) << 12) + k0 + (gsw << 3);
            const short* gpB = W + ((size_t)(j0 + row) << 12) + k0 + (gsw << 3);
            __builtin_amdgcn_global_load_lds(
                (const __attribute__((address_space(1))) void*)gpA,
                (__attribute__((address_space(3))) void*)(As + (c << 3)), 16, 0, 0);
            __builtin_amdgcn_global_load_lds(
                (const __attribute__((address_space(1))) void*)gpB,
                (__attribute__((address_space(3))) void*)(Bs + (c << 3)), 16, 0, 0);
        }
        __syncthreads();
#pragma unroll
        for (int ks2 = 0; ks2 < 2; ++ks2) {
            bf16x8 af[4], bfr[4];
#pragma unroll
            for (int mi = 0; mi < 4; ++mi) {
                int row = (wm << 6) + (mi << 4) + l16;
                int q = (ks2 << 2) + quad;
                int sl = q ^ (row & 7);
                af[mi] = *(const bf16x8*)&As[(row << 6) + (sl << 3)];
            }
#pragma unroll
            for (int ni = 0; ni < 4; ++ni) {
                int row = (wn << 6) + (ni << 4) + l16;
                int q = (ks2 << 2) + quad;
                int sl = q ^ (row & 7);
                bfr[ni] = *(const bf16x8*)&Bs[(row << 6) + (sl << 3)];
            }
#pragma unroll
            for (int mi = 0; mi < 4; ++mi)
#pragma unroll
                for (int ni = 0; ni < 4; ++ni)
                    acc[mi][ni] = __builtin_amdgcn_mfma_f32_16x16x32_bf16(
                        af[mi], bfr[ni], acc[mi][ni], 0, 0, 0);
        }
        __syncthreads();
    }

    float* Pp = P + ((size_t)ks << 20);
#pragma unroll
    for (int mi = 0; mi < 4; ++mi)
#pragma unroll
        for (int ni = 0; ni < 4; ++ni) {
            int col = j0 + (wn << 6) + (ni << 4) + l16;
#pragma unroll
            for (int r = 0; r < 4; ++r) {
                int row = m0 + (wm << 6) + (mi << 4) + (quad << 2) + r;
                Pp[(size_t)row * 256 + col] = acc[mi][ni][r];
            }
        }
}

// ---------------------------------------------------------------------------
// K3: fused split-K reduce + noise + ReLU + MLP + log_softmax.
// 8 rows/block, 512 blocks. Weight-stationary threads.
// ---------------------------------------------------------------------------
__global__ __launch_bounds__(256) void k_mlp(
    const float* __restrict__ P,      // (8,4096,256)
    const float* __restrict__ a_mat,  // (256,5,5)
    const float* __restrict__ noise,  // (256,5)
    const float* __restrict__ fc1_w, const float* __restrict__ fc1_b,
    const float* __restrict__ fc2_w, const float* __restrict__ fc2_b,
    const float* __restrict__ out_w, const float* __restrict__ out_b,
    float* __restrict__ out)          // (4096,10)
{
    __shared__ __align__(16) float Rt[8][260];
    __shared__ float P1[2][8][132];
    __shared__ __align__(16) float H2[8][132];
    __shared__ float P2[4][8][68];
    __shared__ __align__(16) float H3[8][68];
    __shared__ float LG[8][12];
    __shared__ float mrow[8], srow[8];
    __shared__ float nts[256];
    int t = threadIdx.x;
    int b0 = blockIdx.x * 8;

    // noise_term[j]
    {
        float nt = 0.f;
#pragma unroll
        for (int c = 0; c < 5; ++c) {
            float ar = 0.f;
#pragma unroll
            for (int m = 0; m < 5; ++m) ar += a_mat[t * 25 + c * 5 + m];
            nt += noise[t * 5 + c] * ar;
        }
        nts[t] = nt;
    }
    __syncthreads();

    // stage R rows: sum over 8 K-slices + noise + relu
    for (int i = t; i < 512; i += 256) {
        int r = i >> 6;
        int c4 = i & 63;
        size_t base = (size_t)(b0 + r) * 256 + c4 * 4;
        float4 sum = *(const float4*)&nts[c4 * 4];
#pragma unroll
        for (int ks = 0; ks < 8; ++ks) {
            float4 p = *(const float4*)(P + ((size_t)ks << 20) + base);
            sum.x += p.x; sum.y += p.y; sum.z += p.z; sum.w += p.w;
        }
        sum.x = fmaxf(sum.x, 0.f); sum.y = fmaxf(sum.y, 0.f);
        sum.z = fmaxf(sum.z, 0.f); sum.w = fmaxf(sum.w, 0.f);
        *(float4*)&Rt[r][c4 * 4] = sum;
    }
    __syncthreads();

    // fc1 partials: o = t&127, half = t>>7 (K-half of 128)
    {
        int o = t & 127, h = t >> 7;
        float acc[8];
#pragma unroll
        for (int r = 0; r < 8; ++r) acc[r] = 0.f;
        const float* wr = fc1_w + o * 256 + h * 128;
        for (int c = 0; c < 128; c += 4) {
            float4 wv = *(const float4*)(wr + c);
#pragma unroll
            for (int r = 0; r < 8; ++r) {
                float4 rv = *(const float4*)&Rt[r][h * 128 + c];
                acc[r] += rv.x * wv.x + rv.y * wv.y + rv.z * wv.z + rv.w * wv.w;
            }
        }
#pragma unroll
        for (int r = 0; r < 8; ++r) P1[h][r][o] = acc[r];
    }
    __syncthreads();

    for (int i = t; i < 1024; i += 256) {
        int r = i >> 7, o = i & 127;
        H2[r][o] = fmaxf(P1[0][r][o] + P1[1][r][o] + fc1_b[o], 0.f);
    }
    __syncthreads();

    // fc2 partials: o = t&63, q = t>>6 (K-quarter of 32)
    {
        int o = t & 63, q = t >> 6;
        float acc[8];
#pragma unroll
        for (int r = 0; r < 8; ++r) acc[r] = 0.f;
        const float* wr = fc2_w + o * 128 + q * 32;
        for (int c = 0; c < 32; c += 4) {
            float4 wv = *(const float4*)(wr + c);
#pragma unroll
            for (int r = 0; r < 8; ++r) {
                float4 rv = *(const float4*)&H2[r][q * 32 + c];
                acc[r] += rv.x * wv.x + rv.y * wv.y + rv.z * wv.z + rv.w * wv.w;
            }
        }
#pragma unroll
        for (int r = 0; r < 8; ++r) P2[q][r][o] = acc[r];
    }
    __syncthreads();

    for (int i = t; i < 512; i += 256) {
        int r = i >> 6, o = i & 63;
        H3[r][o] = fmaxf(P2[0][r][o] + P2[1][r][o] + P2[2][r][o] + P2[3][r][o]
                         + fc2_b[o], 0.f);
    }
    __syncthreads();

    if (t < 80) {
        int r = t & 7, o = t >> 3;
        float s = out_b[o];
        const float* wpt = out_w + o * 64;
        for (int c = 0; c < 64; c += 4) {
            float4 wv = *(const float4*)(wpt + c);
            float4 rv = *(const float4*)&H3[r][c];
            s += rv.x * wv.x + rv.y * wv.y + rv.z * wv.z + rv.w * wv.w;
        }
        LG[r][o] = s;
    }
    __syncthreads();

    if (t < 8) {
        float m = -1e30f;
#pragma unroll
        for (int o = 0; o < 10; ++o) m = fmaxf(m, LG[t][o]);
        float s = 0.f;
#pragma unroll
        for (int o = 0; o < 10; ++o) s += expf(LG[t][o] - m);
        mrow[t] = m;
        srow[t] = logf(s);
    }
    __syncthreads();

    if (t < 80) {
        int r = t & 7, o = t >> 3;
        out[(size_t)(b0 + r) * 10 + o] = LG[r][o] - mrow[r] - srow[r];
    }
}

// ---------------------------------------------------------------------------
extern "C" void kernel_launch(void* const* d_in, const int* in_sizes, int n_in,
                              void* d_out, int out_size, void* d_ws, size_t ws_size,
                              hipStream_t stream)
{
    const float* x           = (const float*)d_in[0];
    const float* conv_w      = (const float*)d_in[1];
    const float* conv_b      = (const float*)d_in[2];
    const float* bn_gamma    = (const float*)d_in[3];
    const float* bn_beta     = (const float*)d_in[4];
    const float* bn_mean     = (const float*)d_in[5];
    const float* bn_var      = (const float*)d_in[6];
    const float* cut_w_big   = (const float*)d_in[7];
    const float* cut_w_small = (const float*)d_in[8];
    const float* fc1_w       = (const float*)d_in[9];
    const float* fc1_b       = (const float*)d_in[10];
    const float* fc2_w       = (const float*)d_in[11];
    const float* fc2_b       = (const float*)d_in[12];
    const float* out_w       = (const float*)d_in[13];
    const float* out_b       = (const float*)d_in[14];
    const float* b_mat       = (const float*)d_in[15];
    const float* h_mat       = (const float*)d_in[16];
    const float* a_mat       = (const float*)d_in[17];
    const float* indicator   = (const float*)d_in[18];
    const float* noise       = (const float*)d_in[19];
    float* out = (float*)d_out;

    char* ws = (char*)d_ws;
    short* Fbf = (short*)ws;                     // 32 MB
    short* Wbf = (short*)(ws + 33554432);        // 2 MB
    float* P   = (float*)(ws + 35651584);        // 32 MB (8 x 1M fp32)

    k_build_w<<<4096, 256, 0, stream>>>(cut_w_big, cut_w_small, b_mat, h_mat,
                                        a_mat, indicator, Wbf);
    k_branch<<<16384, 256, 0, stream>>>(x, conv_w, conv_b, bn_gamma, bn_beta,
                                        bn_mean, bn_var, Fbf);
    k_gemm<<<512, 256, 0, stream>>>(Fbf, Wbf, P);
    k_mlp<<<512, 256, 0, stream>>>(P, a_mat, noise, fc1_w, fc1_b, fc2_w, fc2_b,
                                   out_w, out_b, out);
}